// Round 8
// baseline (18103.328 us; speedup 1.0000x reference)
//
#include <hip/hip_runtime.h>

typedef unsigned short u16;
typedef unsigned char u8;
typedef unsigned long long u64;
typedef __attribute__((ext_vector_type(8))) _Float16 half8;
typedef __attribute__((ext_vector_type(4))) float f32x4;
typedef __attribute__((ext_vector_type(4))) unsigned int u32x4;

#define MFMA16(a,b,c) __builtin_amdgcn_mfma_f32_16x16x32_f16((a),(b),(c),0,0,0)

#define S_LEN 2048
#define HS (64*512)    // u16 elements per h buffer [64][512]
#define NB0 4
#define NB1 4
#define NGRP 4
#define NWGL 256
#define NACT 96        // 4 groups x (8 L0 + 16 L1)

// ---------- sync[] int indices ----------
#define SI_FLAGF   0      // fast flags: 4 grp x 32
#define SI_XCDPUB  256
#define SI_ROLETAB 512
#define SI_HS      768    // + grp*32
#define SI_VERD    896    // + grp*32 + role; +31 = group verdict
#define SI_FAILED  1104
#define SI_SUCCESS 1120
#define SI_RUNSAFE 1136
#define SI_FLAGS   1200   // safe flags: 4 grp x 32
#define SI_TOTAL   1344

// ---------- ws layout (bytes), same as R5 ----------
#define OFF_W0P  0
#define OFF_W1P  2097152
#define OFF_T0   6291456
#define OFF_B1   6422528
#define OFF_PIDX 6430720
#define OFF_H0   6561792
#define OFF_H1   6823936
#define OFF_SYNC 7086080

__device__ __forceinline__ u16 f2h(float f) {
  _Float16 h = (_Float16)f;
  return __builtin_bit_cast(u16, h);
}
__device__ __forceinline__ float sigf(float x)   { return 1.f/(1.f + __expf(-x)); }
__device__ __forceinline__ float tanhf_(float x) { return 2.f/(1.f + __expf(-2.f*x)) - 1.f; }

// ---- scalar coherent helpers ----
__device__ __forceinline__ int ld_sc01(const int* p) {
  int v; asm volatile("global_load_dword %0, %1, off sc0 sc1\ns_waitcnt vmcnt(0)"
                      : "=v"(v) : "v"(p) : "memory"); return v;
}
__device__ __forceinline__ void st_sc01(int* p, int v) {
  asm volatile("global_store_dword %0, %1, off sc0 sc1" :: "v"(p), "v"(v) : "memory");
}
__device__ __forceinline__ int ld_sc0(const int* p) {
  int v; asm volatile("global_load_dword %0, %1, off sc0\ns_waitcnt vmcnt(0)"
                      : "=v"(v) : "v"(p) : "memory"); return v;
}
__device__ __forceinline__ void st_sc0(int* p, int v) {
  asm volatile("global_store_dword %0, %1, off sc0" :: "v"(p), "v"(v) : "memory");
}

// ---- templated data-path ops: LOC -> XCD-L2 (sc0); !LOC -> device scope (sc0 sc1) ----
template<bool LOC> __device__ __forceinline__ u32x4 gld16(const void* p) {
  u32x4 d;
  if constexpr (LOC) asm volatile("global_load_dwordx4 %0, %1, off sc0" : "=&v"(d) : "v"(p) : "memory");
  else               asm volatile("global_load_dwordx4 %0, %1, off sc0 sc1" : "=&v"(d) : "v"(p) : "memory");
  return d;
}
template<bool LOC> __device__ __forceinline__ void sth4(void* p, const float* hv) {
  union { u64 q; _Float16 h[4]; } u;
  u.h[0] = (_Float16)hv[0]; u.h[1] = (_Float16)hv[1];
  u.h[2] = (_Float16)hv[2]; u.h[3] = (_Float16)hv[3];
  if constexpr (LOC) asm volatile("global_store_dwordx2 %0, %1, off sc0" :: "v"(p), "v"(u.q) : "memory");
  else               asm volatile("global_store_dwordx2 %0, %1, off sc0 sc1" :: "v"(p), "v"(u.q) : "memory");
}
template<bool LOC> __device__ __forceinline__ void stflag(int* p, int v) {
  if constexpr (LOC) st_sc0(p, v); else st_sc01(p, v);
}
// capped poll: true = ready, false = failed/cap (terminal)
template<bool LOC> __device__ __forceinline__ bool pollc(const int* fgrp, const int* failed,
                                                         int lane, int nA, int nB) {
  const int idx = lane & 31;
  const int* p = fgrp + ((idx < 16) ? (idx & 7) : idx);
  const int need = (idx < 16) ? nA : nB;
  for (int outer = 0; outer < 2000; ++outer) {
    for (int inner = 0; inner < 64; ++inner) {
      int v = LOC ? ld_sc0(p) : ld_sc01(p);
      if (__all(v >= need)) return true;
    }
    if (ld_sc01(failed)) return false;
  }
  return false;
}

// ---------- prep ----------
__global__ void k_prep(const float* __restrict__ Wih, const float* __restrict__ Whh,
                       const float* __restrict__ bih, const float* __restrict__ bhh,
                       u16* __restrict__ W0p, u16* __restrict__ W1p,
                       float* __restrict__ b1, u16* __restrict__ hz, int* __restrict__ sync)
{
  int i = blockIdx.x * blockDim.x + threadIdx.x;
  int st = gridDim.x * blockDim.x;
  for (int e = i; e < 8*4*4*16*512; e += st) {
    int k = e & 511, m = (e >> 9) & 15, g = (e >> 13) & 3, wv = (e >> 15) & 3, wgi = e >> 17;
    int row = g*512 + (wgi*4 + wv)*16 + m;
    W0p[e] = f2h(Whh[row*512 + k]);
  }
  for (int e = i; e < 16*2*2*4*16*512; e += st) {
    int k = e & 511, m = (e >> 9) & 15, g = (e >> 13) & 3, kh = (e >> 15) & 1,
        ch = (e >> 16) & 1, wgi = e >> 17;
    int row = g*512 + wgi*32 + ch*16 + m;
    const float* src = kh ? Whh : Wih;
    W1p[e] = f2h(src[2048*512 + row*512 + k]);
  }
  for (int e = i; e < 4*512; e += st) b1[e] = bih[2048 + e] + bhh[2048 + e];
  for (int e = i; e < (NB0 + NB1)*HS; e += st) hz[e] = 0;
  for (int e = i; e < SI_TOTAL; e += st) sync[e] = 0;
}

// ---------- pidx ----------
__global__ void k_pidx(const int* __restrict__ inp32, u8* __restrict__ pidx)
{
  __shared__ int is64s;
  if (threadIdx.x == 0) {
    int z = 0;
    for (int t = 0; t < 64; ++t) z |= inp32[2*t + 1];
    is64s = (z == 0) ? 1 : 0;
  }
  __syncthreads();
  const int is64 = is64s;
  int i = blockIdx.x * blockDim.x + threadIdx.x;
  int st = gridDim.x * blockDim.x;
  for (int e = i; e < S_LEN*64; e += st) {
    int t = e >> 6, b = e & 63;
    int i0 = b * S_LEN + t;
    int i1 = 64 * S_LEN + b * S_LEN + t;
    int a = is64 ? inp32[2*i0] : inp32[i0];
    int c = is64 ? inp32[2*i1] : inp32[i1];
    pidx[e] = (u8)(a * 4 + c);
  }
}

// ---------- table ----------
__global__ void k_table(const float* __restrict__ embed, const float* __restrict__ Wih,
                        const float* __restrict__ bih, const float* __restrict__ bhh,
                        float* __restrict__ T0)
{
  int idx = blockIdx.x * blockDim.x + threadIdx.x;
  if (idx >= 16*2048) return;
  int p = idx >> 11, gj = idx & 2047;
  const float* ea = embed + (p >> 2) * 512;
  const float* ec = embed + (p & 3) * 512;
  const float* w  = Wih + gj * 512;
  float acc = bih[gj] + bhh[gj];
  for (int k = 0; k < 512; ++k) acc += (ea[k] + ec[k]) * w[k];
  T0[p * 2048 + gj] = acc;
}

// ================= fast-kernel layer bodies (capped, abortable) =================
template<bool LOC>
__device__ bool l0_fast(const u16* __restrict__ W0p, const float* __restrict__ T0,
                        const u8* __restrict__ pidx, u16* __restrict__ h0b,
                        int* fgrp, int* failed, u8* smem, int grp, int wgi)
{
  const int tid = threadIdx.x;
  const int lane = tid & 63, wave = tid >> 6;
  const int mrow = lane & 15;
  const int m4 = (lane >> 4) * 4;
  const int q16 = (lane >> 4) * 16;
  const int swm = (mrow & 7) << 4;
  int* s_ok = (int*)(smem + 40960);
  const int jc = (wgi*4 + wave) * 16;
  const u16* wbase = W0p + (wgi*4 + wave) * 32768;
  half8 wa[4][16];
#pragma unroll
  for (int g = 0; g < 4; ++g)
#pragma unroll
    for (int ks = 0; ks < 16; ++ks)
      wa[g][ks] = *(const half8*)(wbase + (g*16 + mrow)*512 + ks*32 + (lane >> 4)*8);
  const int bg = grp*16 + mrow;
  float cs[4] = {0.f, 0.f, 0.f, 0.f};
  int p = pidx[bg];
  f32x4 tg[4];
#pragma unroll
  for (int g = 0; g < 4; ++g) tg[g] = *(const f32x4*)(T0 + p*2048 + jc + m4 + g*512);
  for (int t = 0; t < S_LEN; ++t) {
    bool ok = pollc<LOC>(fgrp, failed, lane, t, t - (NB0 - 1));
    if (lane == 0) s_ok[wave] = ok ? 1 : 0;
    const u16* hr = h0b + ((t + NB0 - 1) % NB0) * HS;
    u16*       hw = h0b + (t % NB0) * HS;
    if (ok) {
      const char* gs = (const char*)hr + grp*16384;
      u32x4 d0 = gld16<LOC>(gs + tid*16);
      u32x4 d1 = gld16<LOC>(gs + tid*16 + 4096);
      u32x4 d2 = gld16<LOC>(gs + tid*16 + 8192);
      u32x4 d3 = gld16<LOC>(gs + tid*16 + 12288);
      asm volatile("s_waitcnt vmcnt(0)" ::: "memory");
      __builtin_amdgcn_sched_barrier(0);
      *(u32x4*)(smem + tid*16        ) = d0;
      *(u32x4*)(smem + tid*16 +  4096) = d1;
      *(u32x4*)(smem + tid*16 +  8192) = d2;
      *(u32x4*)(smem + tid*16 + 12288) = d3;
    }
    __syncthreads();
    if (!(s_ok[0] & s_ok[1] & s_ok[2] & s_ok[3])) {
      if (tid == 0) st_sc01(failed, 1);
      return false;
    }
    half8 bf[16];
#pragma unroll
    for (int ks = 0; ks < 16; ++ks)
      bf[ks] = *(const half8*)(smem + mrow*1024 + ((ks*64 + q16) ^ swm));
    f32x4 acc[4] = {{0,0,0,0},{0,0,0,0},{0,0,0,0},{0,0,0,0}};
#pragma unroll
    for (int ks = 0; ks < 16; ++ks)
#pragma unroll
      for (int g = 0; g < 4; ++g)
        acc[g] = MFMA16(wa[g][ks], bf[ks], acc[g]);
    float hv[4];
#pragma unroll
    for (int r = 0; r < 4; ++r) {
      float gi = acc[0][r] + tg[0][r];
      float gf = acc[1][r] + tg[1][r];
      float gg = acc[2][r] + tg[2][r];
      float go = acc[3][r] + tg[3][r];
      float cc = sigf(gf)*cs[r] + sigf(gi)*tanhf_(gg);
      cs[r] = cc;
      hv[r] = sigf(go)*tanhf_(cc);
    }
    sth4<LOC>((char*)hw + bg*1024 + (((jc + m4)*2) ^ ((bg & 7) << 4)), hv);
    if (t + 1 < S_LEN) {
      int pn = pidx[(t+1)*64 + bg];
#pragma unroll
      for (int g = 0; g < 4; ++g)
        tg[g] = *(const f32x4*)(T0 + pn*2048 + jc + m4 + g*512);
    }
    asm volatile("s_waitcnt vmcnt(0)" ::: "memory");
    __syncthreads();
    if (tid == 0) stflag<LOC>(fgrp + wgi, t + 1);
#pragma unroll
    for (int g = 0; g < 4; ++g)
#pragma unroll
      for (int ks = 0; ks < 16; ++ks)
        asm volatile("" : "+v"(wa[g][ks]));
  }
  return true;
}

template<bool LOC>
__device__ bool l1_fast(const u16* __restrict__ W1p, const float* __restrict__ b1,
                        u16* __restrict__ h0b, u16* __restrict__ h1b,
                        int* fgrp, int* failed, u8* smem, int grp, int wgi)
{
  const int tid = threadIdx.x;
  const int lane = tid & 63, wave = tid >> 6;
  const int mrow = lane & 15;
  const int m4 = (lane >> 4) * 4;
  const int q16 = (lane >> 4) * 16;
  const int swm = (mrow & 7) << 4;
  int* s_ok = (int*)(smem + 40960);
  const int kh = wave & 1, ch = wave >> 1;
  const int jc = wgi*32 + ch*16;
  const u16* wbase = W1p + ((wgi*2 + ch)*2 + kh) * 32768;
  half8 wa[4][16];
#pragma unroll
  for (int g = 0; g < 4; ++g)
#pragma unroll
    for (int ks = 0; ks < 16; ++ks)
      wa[g][ks] = *(const half8*)(wbase + (g*16 + mrow)*512 + ks*32 + (lane >> 4)*8);
  const int bg = grp*16 + mrow;
  f32x4* xbuf = (f32x4*)(smem + 32768);
  f32x4 big[4];
#pragma unroll
  for (int g = 0; g < 4; ++g) big[g] = *(const f32x4*)(b1 + g*512 + jc + m4);
  const int shalf = tid >> 7;
  const int sidx  = tid & 127;
  float cs[4] = {0.f, 0.f, 0.f, 0.f};
  for (int w = 1; w <= S_LEN; ++w) {
    const int u = w - 1;
    bool ok = pollc<LOC>(fgrp, failed, lane, w, w - 1);
    if (lane == 0) s_ok[wave] = ok ? 1 : 0;
    const u16* h0s = h0b + (u % NB0) * HS;
    const u16* h1s = h1b + ((u + NB1 - 1) % NB1) * HS;
    u16* hw = h1b + (u % NB1) * HS;
    if (ok) {
      const char* gs = (const char*)(shalf ? h1s : h0s) + grp*16384;
      char* ls = (char*)smem + shalf*16384;
      u32x4 d[8];
#pragma unroll
      for (int j = 0; j < 8; ++j) d[j] = gld16<LOC>(gs + sidx*16 + j*2048);
      asm volatile("s_waitcnt vmcnt(0)" ::: "memory");
      __builtin_amdgcn_sched_barrier(0);
#pragma unroll
      for (int j = 0; j < 8; ++j) *(u32x4*)(ls + sidx*16 + j*2048) = d[j];
    }
    __syncthreads();
    if (!(s_ok[0] & s_ok[1] & s_ok[2] & s_ok[3])) {
      if (tid == 0) st_sc01(failed, 1);
      return false;
    }
    const char* lsrc = (const char*)smem + kh*16384;
    half8 bf[16];
#pragma unroll
    for (int ks = 0; ks < 16; ++ks)
      bf[ks] = *(const half8*)(lsrc + mrow*1024 + ((ks*64 + q16) ^ swm));
    f32x4 acc[4] = {{0,0,0,0},{0,0,0,0},{0,0,0,0},{0,0,0,0}};
#pragma unroll
    for (int ks = 0; ks < 16; ++ks)
#pragma unroll
      for (int g = 0; g < 4; ++g)
        acc[g] = MFMA16(wa[g][ks], bf[ks], acc[g]);
    if (kh == 1) {
#pragma unroll
      for (int g = 0; g < 4; ++g)
        xbuf[(ch*4 + g)*64 + lane] = acc[g];
    }
    __syncthreads();
    if (kh == 0) {
#pragma unroll
      for (int g = 0; g < 4; ++g)
        acc[g] += xbuf[(ch*4 + g)*64 + lane];
      float hv[4];
#pragma unroll
      for (int r = 0; r < 4; ++r) {
        float gi = acc[0][r] + big[0][r];
        float gf = acc[1][r] + big[1][r];
        float gg = acc[2][r] + big[2][r];
        float go = acc[3][r] + big[3][r];
        float cc = sigf(gf)*cs[r] + sigf(gi)*tanhf_(gg);
        cs[r] = cc;
        hv[r] = sigf(go)*tanhf_(cc);
      }
      sth4<LOC>((char*)hw + bg*1024 + (((jc + m4)*2) ^ ((bg & 7) << 4)), hv);
    }
    asm volatile("s_waitcnt vmcnt(0)" ::: "memory");
    __syncthreads();
    if (tid == 0) stflag<LOC>(fgrp + 16 + wgi, w);
#pragma unroll
    for (int g = 0; g < 4; ++g)
#pragma unroll
      for (int ks = 0; ks < 16; ++ks)
        asm volatile("" : "+v"(wa[g][ks]));
  }
  return true;
}

// ---------- fast kernel: capped discovery + XCD-local loop + success counting ----------
__global__ __launch_bounds__(256, 1) void k_fast(
    const u16* __restrict__ W0p, const u16* __restrict__ W1p,
    const float* __restrict__ T0, const float* __restrict__ b1,
    const u8* __restrict__ pidx,
    u16* __restrict__ h0b, u16* __restrict__ h1b, int* __restrict__ sync)
{
  __shared__ __align__(16) u8 smem[41024];
  __shared__ int sinfo;
  const int tid = threadIdx.x, bid = blockIdx.x;
  int* flags   = sync + SI_FLAGF;
  int* xcdpub  = sync + SI_XCDPUB;
  int* roleTab = sync + SI_ROLETAB;
  int* failed  = sync + SI_FAILED;
  int* succ    = sync + SI_SUCCESS;

  // phase 1: publish XCD id (unconditional)
  if (tid == 0) {
    int xcd;
    asm volatile("s_getreg_b32 %0, hwreg(HW_REG_XCC_ID)" : "=s"(xcd));
    st_sc01(xcdpub + bid, (xcd & 7) + 1);
  }
  // phase 2: coordinator assigns (all waits capped)
  if (bid == 0) {
    int* lmap = (int*)smem;
    for (int i = tid; i < NWGL; i += 256) {
      int v = 0;
      for (int it = 0; it < 200000 && v == 0; ++it) v = ld_sc01(xcdpub + i);
      lmap[i] = v - 1;   // -1 if never seen
    }
    __syncthreads();
    if (tid == 0) {
      int cnt[8] = {0,0,0,0,0,0,0,0};
      for (int i = 0; i < NWGL; ++i) { int x = lmap[i]; if (x >= 0 && x < 8) cnt[x]++; }
      int gx[NGRP], gl[NGRP], used = 0;
      for (int g = 0; g < NGRP; ++g) {
        int best = 0, bc = -1;
        for (int x = 0; x < 8; ++x)
          if (!((used >> x) & 1) && cnt[x] > bc) { bc = cnt[x]; best = x; }
        gx[g] = best; used |= 1 << best;
        gl[g] = (bc >= 24) ? 1 : 0;
      }
      int rc[NGRP] = {0,0,0,0};
      for (int i = 0; i < NWGL; ++i) {
        int x = lmap[i], as = 1;
        if (x >= 0 && x < 8)
          for (int g = 0; g < NGRP; ++g)
            if (gl[g] && gx[g] == x && rc[g] < 24) {
              as = (1 << 30) | (g << 16) | (rc[g] << 8) | 1; rc[g]++; break;
            }
        lmap[i] = as;
      }
      for (int g = 0; g < NGRP; ++g)
        if (!gl[g])
          for (int i = 0; i < NWGL && rc[g] < 24; ++i)
            if (lmap[i] == 1) { lmap[i] = (1 << 30) | (g << 16) | (rc[g] << 8); rc[g]++; }
      if (rc[0] + rc[1] + rc[2] + rc[3] != NACT) {
        for (int i = 0; i < NWGL; ++i) lmap[i] = 1;   // abort -> all surplus
        st_sc01(failed, 1);
      }
      for (int i = 0; i < NWGL; ++i) st_sc01(roleTab + i, lmap[i]);
    }
    __syncthreads();
  }
  // phase 3: read my assignment (capped)
  if (tid == 0) {
    int v = 0;
    for (int it = 0; it < 400000 && v == 0; ++it) {
      v = ld_sc01(roleTab + bid);
      if (v == 0) __builtin_amdgcn_s_sleep(1);
    }
    if (v == 0) st_sc01(failed, 1);
    sinfo = v;
  }
  __syncthreads();
  const int info = sinfo;
  if (!(info & (1 << 30))) return;   // surplus or cap
  const int grp = (info >> 16) & 0xff, role = (info >> 8) & 0xff;
  int loc = info & 1;
  __syncthreads();
  // phase 4: sc0 handshake; role-0 publishes the single group verdict
  if (loc) {
    int* hsA   = sync + SI_HS + grp*32;
    int* verdg = sync + SI_VERD + grp*32;
    if (tid == 0) {
      if (role == 0) st_sc0(hsA, 1);
      int ok = 0;
      for (int it = 0; it < 3000; ++it)
        if (ld_sc0(hsA) == 1) { ok = 1; break; }
      st_sc01(verdg + role, 1 + ok);
      if (role == 0) {
        int all = 1;
        for (int r = 0; r < 24; ++r) {
          int v = 0;
          for (int it = 0; it < 200000 && v == 0; ++it) v = ld_sc01(verdg + r);
          if (v != 2) { all = 0; break; }
        }
        st_sc01(verdg + 31, 1 + all);
      }
      int gv = 0;
      for (int it = 0; it < 400000 && gv == 0; ++it) gv = ld_sc01(verdg + 31);
      sinfo = (gv == 2) ? 1 : 0;
    }
    __syncthreads();
    loc = sinfo;
  }

  int* fgrp = flags + grp * 32;
  bool done;
  if (role < 8) {
    done = loc ? l0_fast<true >(W0p, T0, pidx, h0b, fgrp, failed, smem, grp, role)
               : l0_fast<false>(W0p, T0, pidx, h0b, fgrp, failed, smem, grp, role);
  } else {
    done = loc ? l1_fast<true >(W1p, b1, h0b, h1b, fgrp, failed, smem, grp, role - 8)
               : l1_fast<false>(W1p, b1, h0b, h1b, fgrp, failed, smem, grp, role - 8);
  }
  if (done && tid == 0)
    __hip_atomic_fetch_add(succ, 1, __ATOMIC_RELAXED, __HIP_MEMORY_SCOPE_AGENT);
}

// ---------- check: arm safe path + re-zero h rings if fast failed ----------
__global__ __launch_bounds__(256) void k_check(int* __restrict__ sync, u64* __restrict__ hz)
{
  const int i = blockIdx.x * blockDim.x + threadIdx.x;
  const int st = gridDim.x * blockDim.x;
  const int s = sync[SI_SUCCESS];
  if (i == 0) sync[SI_RUNSAFE] = (s == NACT) ? 0 : 1;
  if (s != NACT) {
    for (int e = i; e < (NB0 + NB1) * HS / 4; e += st) hz[e] = 0;
  }
}

// ---------- safe kernel: verbatim R5 (12.68 ms proven), behind a guard ----------
__device__ __forceinline__ u32x4 gload16_s(const void* p) {
  u32x4 d;
  asm volatile("global_load_dwordx4 %0, %1, off sc0 sc1"
               : "=&v"(d) : "v"(p) : "memory");
  return d;
}
__device__ __forceinline__ void store_h4_s(u16* p, const float* hv) {
  union { u64 q; _Float16 h[4]; } u;
  u.h[0] = (_Float16)hv[0]; u.h[1] = (_Float16)hv[1];
  u.h[2] = (_Float16)hv[2]; u.h[3] = (_Float16)hv[3];
  __hip_atomic_store((u64*)p, u.q, __ATOMIC_RELAXED, __HIP_MEMORY_SCOPE_AGENT);
}
__device__ __forceinline__ void poll_s(const int* fgrp, int lane, int nA, int nB) {
  const int idx = lane & 31;
  const int* p = fgrp + ((idx < 16) ? (idx & 7) : idx);
  const int need = (idx < 16) ? nA : nB;
  for (;;) {
    int v = __hip_atomic_load(p, __ATOMIC_RELAXED, __HIP_MEMORY_SCOPE_AGENT);
    if (__all(v >= need)) break;
  }
  asm volatile("" ::: "memory");
}

__global__ __launch_bounds__(256, 1) void k_safe(
    const u16* __restrict__ W0p, const u16* __restrict__ W1p,
    const float* __restrict__ T0, const float* __restrict__ b1,
    const u8* __restrict__ pidx,
    u16* __restrict__ h0b, u16* __restrict__ h1b, int* __restrict__ sync)
{
  __shared__ __align__(16) u8 smem[40960];
  __shared__ int sgo;
  const int tid  = threadIdx.x;
  if (tid == 0) sgo = sync[SI_RUNSAFE];
  __syncthreads();
  if (!sgo) return;
  int* flags = sync + SI_FLAGS;

  const int lane = tid & 63, wave = tid >> 6;
  const int wg   = blockIdx.x;
  const int mrow = lane & 15;
  const int m4   = (lane >> 4) * 4;
  const int q16  = (lane >> 4) * 16;
  const int swm  = (mrow & 7) << 4;

  if (wg < 32) {
    const int grp = wg >> 3, wgi = wg & 7;
    int* fgrp = flags + grp*32;
    const int jc = (wgi*4 + wave) * 16;
    const u16* wbase = W0p + (wgi*4 + wave) * 32768;
    half8 wa[4][16];
#pragma unroll
    for (int g = 0; g < 4; ++g)
#pragma unroll
      for (int ks = 0; ks < 16; ++ks)
        wa[g][ks] = *(const half8*)(wbase + (g*16 + mrow)*512 + ks*32 + (lane >> 4)*8);
    const int bg = grp*16 + mrow;
    float cs[4] = {0.f, 0.f, 0.f, 0.f};
    int p = pidx[bg];
    f32x4 tg[4];
#pragma unroll
    for (int g = 0; g < 4; ++g) tg[g] = *(const f32x4*)(T0 + p*2048 + jc + m4 + g*512);
    for (int t = 0; t < S_LEN; ++t) {
      poll_s(fgrp, lane, t, t - (NB0 - 1));
      const u16* hr = h0b + ((t + NB0 - 1) % NB0) * HS;
      u16*       hw = h0b + (t % NB0) * HS;
      {
        const char* gs = (const char*)hr + grp*16384;
        u32x4 d0 = gload16_s(gs + tid*16);
        u32x4 d1 = gload16_s(gs + tid*16 + 4096);
        u32x4 d2 = gload16_s(gs + tid*16 + 8192);
        u32x4 d3 = gload16_s(gs + tid*16 + 12288);
        asm volatile("s_waitcnt vmcnt(0)" ::: "memory");
        __builtin_amdgcn_sched_barrier(0);
        *(u32x4*)(smem + tid*16        ) = d0;
        *(u32x4*)(smem + tid*16 +  4096) = d1;
        *(u32x4*)(smem + tid*16 +  8192) = d2;
        *(u32x4*)(smem + tid*16 + 12288) = d3;
      }
      __syncthreads();
      half8 bf[16];
#pragma unroll
      for (int ks = 0; ks < 16; ++ks)
        bf[ks] = *(const half8*)(smem + mrow*1024 + ((ks*64 + q16) ^ swm));
      f32x4 acc[4] = {{0,0,0,0},{0,0,0,0},{0,0,0,0},{0,0,0,0}};
#pragma unroll
      for (int ks = 0; ks < 16; ++ks)
#pragma unroll
        for (int g = 0; g < 4; ++g)
          acc[g] = MFMA16(wa[g][ks], bf[ks], acc[g]);
      float hv[4];
#pragma unroll
      for (int r = 0; r < 4; ++r) {
        float gi = acc[0][r] + tg[0][r];
        float gf = acc[1][r] + tg[1][r];
        float gg = acc[2][r] + tg[2][r];
        float go = acc[3][r] + tg[3][r];
        float cc = sigf(gf)*cs[r] + sigf(gi)*tanhf_(gg);
        cs[r] = cc;
        hv[r] = sigf(go)*tanhf_(cc);
      }
      store_h4_s((u16*)((char*)hw + bg*1024 + (((jc + m4)*2) ^ ((bg & 7) << 4))), hv);
      if (t + 1 < S_LEN) {
        int pn = pidx[(t+1)*64 + bg];
#pragma unroll
        for (int g = 0; g < 4; ++g)
          tg[g] = *(const f32x4*)(T0 + pn*2048 + jc + m4 + g*512);
      }
      asm volatile("s_waitcnt vmcnt(0)" ::: "memory");
      __syncthreads();
      if (tid == 0)
        __hip_atomic_store(fgrp + wgi, t + 1, __ATOMIC_RELAXED, __HIP_MEMORY_SCOPE_AGENT);
#pragma unroll
      for (int g = 0; g < 4; ++g)
#pragma unroll
        for (int ks = 0; ks < 16; ++ks)
          asm volatile("" : "+v"(wa[g][ks]));
    }
  } else {
    const int w1 = wg - 32;
    const int grp = w1 >> 4, wgi = w1 & 15;
    int* fgrp = flags + grp*32;
    const int kh = wave & 1, ch = wave >> 1;
    const int jc = wgi*32 + ch*16;
    const u16* wbase = W1p + ((wgi*2 + ch)*2 + kh) * 32768;
    half8 wa[4][16];
#pragma unroll
    for (int g = 0; g < 4; ++g)
#pragma unroll
      for (int ks = 0; ks < 16; ++ks)
        wa[g][ks] = *(const half8*)(wbase + (g*16 + mrow)*512 + ks*32 + (lane >> 4)*8);
    const int bg = grp*16 + mrow;
    f32x4* xbuf = (f32x4*)(smem + 32768);
    f32x4 big[4];
#pragma unroll
    for (int g = 0; g < 4; ++g) big[g] = *(const f32x4*)(b1 + g*512 + jc + m4);
    const int shalf = tid >> 7;
    const int sidx  = tid & 127;
    float cs[4] = {0.f, 0.f, 0.f, 0.f};
    for (int w = 1; w <= S_LEN; ++w) {
      const int u = w - 1;
      poll_s(fgrp, lane, w, w - 1);
      const u16* h0s = h0b + (u % NB0) * HS;
      const u16* h1s = h1b + ((u + NB1 - 1) % NB1) * HS;
      u16* hw = h1b + (u % NB1) * HS;
      {
        const char* gs = (const char*)(shalf ? h1s : h0s) + grp*16384;
        char* ls = (char*)smem + shalf*16384;
        u32x4 d[8];
#pragma unroll
        for (int j = 0; j < 8; ++j) d[j] = gload16_s(gs + sidx*16 + j*2048);
        asm volatile("s_waitcnt vmcnt(0)" ::: "memory");
        __builtin_amdgcn_sched_barrier(0);
#pragma unroll
        for (int j = 0; j < 8; ++j) *(u32x4*)(ls + sidx*16 + j*2048) = d[j];
      }
      __syncthreads();
      const char* lsrc = (const char*)smem + kh*16384;
      half8 bf[16];
#pragma unroll
      for (int ks = 0; ks < 16; ++ks)
        bf[ks] = *(const half8*)(lsrc + mrow*1024 + ((ks*64 + q16) ^ swm));
      f32x4 acc[4] = {{0,0,0,0},{0,0,0,0},{0,0,0,0},{0,0,0,0}};
#pragma unroll
      for (int ks = 0; ks < 16; ++ks)
#pragma unroll
        for (int g = 0; g < 4; ++g)
          acc[g] = MFMA16(wa[g][ks], bf[ks], acc[g]);
      if (kh == 1) {
#pragma unroll
        for (int g = 0; g < 4; ++g)
          xbuf[(ch*4 + g)*64 + lane] = acc[g];
      }
      __syncthreads();
      if (kh == 0) {
#pragma unroll
        for (int g = 0; g < 4; ++g)
          acc[g] += xbuf[(ch*4 + g)*64 + lane];
        float hv[4];
#pragma unroll
        for (int r = 0; r < 4; ++r) {
          float gi = acc[0][r] + big[0][r];
          float gf = acc[1][r] + big[1][r];
          float gg = acc[2][r] + big[2][r];
          float go = acc[3][r] + big[3][r];
          float cc = sigf(gf)*cs[r] + sigf(gi)*tanhf_(gg);
          cs[r] = cc;
          hv[r] = sigf(go)*tanhf_(cc);
        }
        store_h4_s((u16*)((char*)hw + bg*1024 + (((jc + m4)*2) ^ ((bg & 7) << 4))), hv);
      }
      asm volatile("s_waitcnt vmcnt(0)" ::: "memory");
      __syncthreads();
      if (tid == 0)
        __hip_atomic_store(fgrp + 16 + wgi, w, __ATOMIC_RELAXED, __HIP_MEMORY_SCOPE_AGENT);
#pragma unroll
      for (int g = 0; g < 4; ++g)
#pragma unroll
        for (int ks = 0; ks < 16; ++ks)
          asm volatile("" : "+v"(wa[g][ks]));
    }
  }
}

// ---------- finalize: LayerNorm + projection from h1[2047] (fp16, swizzled rows) ----------
__global__ __launch_bounds__(256) void k_final(
    const u16* __restrict__ h1last, const float* __restrict__ ln_g,
    const float* __restrict__ ln_b, const float* __restrict__ Wp,
    const float* __restrict__ bp, float* __restrict__ out)
{
  __shared__ float sb[8];
  __shared__ float sred[4];
  const int b = blockIdx.x, tid = threadIdx.x;
  const char* hrow = (const char*)h1last + b * 1024;
  const int sw = (b & 7) << 4;
  float v1 = (float)*(const _Float16*)(hrow + ((tid*2) ^ sw));
  float v2 = (float)*(const _Float16*)(hrow + (((tid + 256)*2) ^ sw));
  float s1 = v1 + v2, s2 = v1*v1 + v2*v2;
#pragma unroll
  for (int o = 32; o; o >>= 1) { s1 += __shfl_down(s1, o); s2 += __shfl_down(s2, o); }
  if ((tid & 63) == 0) { sb[tid >> 6] = s1; sb[4 + (tid >> 6)] = s2; }
  __syncthreads();
  float S1 = sb[0] + sb[1] + sb[2] + sb[3];
  float S2 = sb[4] + sb[5] + sb[6] + sb[7];
  float mu = S1 * (1.f/512.f);
  float var = S2 * (1.f/512.f) - mu*mu;
  float inv = rsqrtf(var + 1e-5f);
  float acc = ((v1 - mu)*inv*ln_g[tid]       + ln_b[tid])       * Wp[tid]
            + ((v2 - mu)*inv*ln_g[tid + 256] + ln_b[tid + 256]) * Wp[tid + 256];
#pragma unroll
  for (int o = 32; o; o >>= 1) acc += __shfl_down(acc, o);
  if ((tid & 63) == 0) sred[tid >> 6] = acc;
  __syncthreads();
  if (tid == 0) out[b] = sred[0] + sred[1] + sred[2] + sred[3] + bp[0];
}

extern "C" void kernel_launch(void* const* d_in, const int* in_sizes, int n_in,
                              void* d_out, int out_size, void* d_ws, size_t ws_size,
                              hipStream_t stream) {
  (void)in_sizes; (void)n_in; (void)out_size; (void)ws_size;
  const int*   inp   = (const int*)d_in[0];
  const float* embed = (const float*)d_in[1];
  const float* Wih   = (const float*)d_in[2];
  const float* Whh   = (const float*)d_in[3];
  const float* bih   = (const float*)d_in[4];
  const float* bhh   = (const float*)d_in[5];
  const float* ln_g  = (const float*)d_in[6];
  const float* ln_b  = (const float*)d_in[7];
  const float* Wp    = (const float*)d_in[8];
  const float* bp    = (const float*)d_in[9];
  float* out = (float*)d_out;
  char* ws = (char*)d_ws;

  u16*   W0p  = (u16*)  (ws + OFF_W0P);
  u16*   W1p  = (u16*)  (ws + OFF_W1P);
  float* T0   = (float*)(ws + OFF_T0);
  float* b1   = (float*)(ws + OFF_B1);
  u8*    pidx = (u8*)   (ws + OFF_PIDX);
  u16*   h0   = (u16*)  (ws + OFF_H0);
  u16*   h1   = (u16*)  (ws + OFF_H1);
  int*   sync = (int*)  (ws + OFF_SYNC);

  k_prep<<<512, 256, 0, stream>>>(Wih, Whh, bih, bhh, W0p, W1p, b1, h0, sync);
  k_pidx<<<64, 256, 0, stream>>>(inp, pidx);
  k_table<<<128, 256, 0, stream>>>(embed, Wih, bih, bhh, T0);

  k_fast<<<dim3(NWGL), dim3(256), 0, stream>>>(W0p, W1p, T0, b1, pidx, h0, h1, sync);
  k_check<<<64, 256, 0, stream>>>(sync, (u64*)h0);
  k_safe<<<dim3(96), dim3(256), 0, stream>>>(W0p, W1p, T0, b1, pidx, h0, h1, sync);

  // h1[2047] lives in buffer (2047 % 4) == 3
  k_final<<<64, 256, 0, stream>>>(h1 + 3*HS, ln_g, ln_b, Wp, bp, out);
}

// Round 9
// 10085.981 us; speedup vs baseline: 1.7949x; 1.7949x over previous
//
#include <hip/hip_runtime.h>

typedef unsigned short u16;
typedef unsigned char u8;
typedef unsigned long long u64;
typedef __attribute__((ext_vector_type(8))) _Float16 half8;
typedef __attribute__((ext_vector_type(4))) float f32x4;
typedef __attribute__((ext_vector_type(4))) unsigned int u32x4;

#define MFMA16(a,b,c) __builtin_amdgcn_mfma_f32_16x16x32_f16((a),(b),(c),0,0,0)

#define S_LEN 2048
#define HS (64*512)    // u16 elements per h buffer [64][512]
#define NB0 4          // h0 ring buffers
#define NB1 4          // h1 ring buffers
#define NGRP 4         // independent batch groups (16 batch rows each)

// ---------- ws layout (bytes) ----------
#define OFF_W0P  0            // fp16 [8 wgi][4 wv][4 g][16 m][512 k]   2 MB
#define OFF_W1P  2097152      // fp16 [16 wgi][2 ch][2 kh][4 g][16][512] 4 MB
#define OFF_T0   6291456      // f32 [16 pair][4 gate][512 col]         128 KB
#define OFF_B1   6422528      // f32 [4 gate][512 col]                  8 KB
#define OFF_PIDX 6430720      // u8 [2048][64]                          128 KB
#define OFF_H0   6561792      // fp16 4 x [64][512] (row-swizzled)      256 KB
#define OFF_H1   6823936      // fp16 4 x [64][512] (row-swizzled)      256 KB
#define OFF_FLAG 7086080      // int [4 grp][64]: fA[0..31], fB[32..63]

__device__ __forceinline__ u16 f2h(float f) {
  _Float16 h = (_Float16)f;
  return __builtin_bit_cast(u16, h);
}
__device__ __forceinline__ float sigf(float x)   { return 1.f/(1.f + __expf(-x)); }
__device__ __forceinline__ float tanhf_(float x) { return 2.f/(1.f + __expf(-2.f*x)) - 1.f; }

// device-coherent 16B load
__device__ __forceinline__ u32x4 gload16(const void* p) {
  u32x4 d;
  asm volatile("global_load_dwordx4 %0, %1, off sc0 sc1"
               : "=&v"(d) : "v"(p) : "memory");
  return d;
}
// device-coherent 8B store of 4 fp16
__device__ __forceinline__ void store_h4(void* p, const float* hv) {
  union { u64 q; _Float16 h[4]; } u;
  u.h[0] = (_Float16)hv[0]; u.h[1] = (_Float16)hv[1];
  u.h[2] = (_Float16)hv[2]; u.h[3] = (_Float16)hv[3];
  asm volatile("global_store_dwordx2 %0, %1, off sc0 sc1" :: "v"(p), "v"(u.q) : "memory");
}
__device__ __forceinline__ void store_flag(int* p, int v) {
  asm volatile("global_store_dword %0, %1, off sc0 sc1" :: "v"(p), "v"(v) : "memory");
}
// 64-lane poll: lane i watches fgrp[i]; lanes 0..31 need >= nA, 32..63 need >= nB.
// Deadlock-free by construction (global scope, monotonic flags). s_sleep backoff
// cuts read pressure on the flag lines so producer stores land faster.
__device__ __forceinline__ void poll(const int* fgrp, int lane, int nA, int nB) {
  const int* p = fgrp + lane;
  const int need = (lane < 32) ? nA : nB;
  for (;;) {
    int v;
    asm volatile("global_load_dword %0, %1, off sc0 sc1\ns_waitcnt vmcnt(0)"
                 : "=v"(v) : "v"(p) : "memory");
    if (__all(v >= need)) break;
    __builtin_amdgcn_s_sleep(1);
  }
}

// ---------- prep: weight permute+convert, bias sum, zero h, reset flags ----------
__global__ void k_prep(const float* __restrict__ Wih, const float* __restrict__ Whh,
                       const float* __restrict__ bih, const float* __restrict__ bhh,
                       u16* __restrict__ W0p, u16* __restrict__ W1p,
                       float* __restrict__ b1, u16* __restrict__ hz, int* __restrict__ flags)
{
  int i = blockIdx.x * blockDim.x + threadIdx.x;
  int st = gridDim.x * blockDim.x;
  // W0p[wgi][wv][g][m][k] <- Whh0[g*512 + (wgi*4+wv)*16 + m][k]
  for (int e = i; e < 8*4*4*16*512; e += st) {
    int k = e & 511, m = (e >> 9) & 15, g = (e >> 13) & 3, wv = (e >> 15) & 3, wgi = e >> 17;
    int row = g*512 + (wgi*4 + wv)*16 + m;
    W0p[e] = f2h(Whh[row*512 + k]);
  }
  // W1p[wgi][ch][kh][g][m][k] <- (kh?Whh1:Wih1)[g*512 + wgi*32 + ch*16 + m][k]
  for (int e = i; e < 16*2*2*4*16*512; e += st) {
    int k = e & 511, m = (e >> 9) & 15, g = (e >> 13) & 3, kh = (e >> 15) & 1,
        ch = (e >> 16) & 1, wgi = e >> 17;
    int row = g*512 + wgi*32 + ch*16 + m;
    const float* src = kh ? Whh : Wih;
    W1p[e] = f2h(src[2048*512 + row*512 + k]);
  }
  for (int e = i; e < 4*512; e += st) b1[e] = bih[2048 + e] + bhh[2048 + e];
  for (int e = i; e < (NB0 + NB1)*HS; e += st) hz[e] = 0;
  for (int e = i; e < NGRP*64; e += st) flags[e] = 0;
}

// ---------- pidx: pair index per (t,b), int32/int64 auto-detect ----------
__global__ void k_pidx(const int* __restrict__ inp32, u8* __restrict__ pidx)
{
  __shared__ int is64s;
  if (threadIdx.x == 0) {
    int z = 0;
    for (int t = 0; t < 64; ++t) z |= inp32[2*t + 1];
    is64s = (z == 0) ? 1 : 0;
  }
  __syncthreads();
  const int is64 = is64s;
  int i = blockIdx.x * blockDim.x + threadIdx.x;
  int st = gridDim.x * blockDim.x;
  for (int e = i; e < S_LEN*64; e += st) {
    int t = e >> 6, b = e & 63;
    int i0 = b * S_LEN + t;
    int i1 = 64 * S_LEN + b * S_LEN + t;
    int a = is64 ? inp32[2*i0] : inp32[i0];
    int c = is64 ? inp32[2*i1] : inp32[i1];
    pidx[e] = (u8)(a * 4 + c);
  }
}

// ---------- table: T0[p][g*512+j] = (embed[a]+embed[c]) . Wih0[g*512+j] + bias0 ----------
__global__ void k_table(const float* __restrict__ embed, const float* __restrict__ Wih,
                        const float* __restrict__ bih, const float* __restrict__ bhh,
                        float* __restrict__ T0)
{
  int idx = blockIdx.x * blockDim.x + threadIdx.x;
  if (idx >= 16*2048) return;
  int p = idx >> 11, gj = idx & 2047;
  const float* ea = embed + (p >> 2) * 512;
  const float* ec = embed + (p & 3) * 512;
  const float* w  = Wih + gj * 512;
  float acc = bih[gj] + bhh[gj];
  for (int k = 0; k < 512; ++k) acc += (ea[k] + ec[k]) * w[k];
  T0[p * 2048 + gj] = acc;
}

// ---------- persistent 2-layer LSTM: 4 batch groups, per-wave flag sync ----------
__global__ __launch_bounds__(256, 1) void k_lstm(
    const u16* __restrict__ W0p, const u16* __restrict__ W1p,
    const float* __restrict__ T0, const float* __restrict__ b1,
    const u8* __restrict__ pidx,
    u16* __restrict__ h0b, u16* __restrict__ h1b, int* __restrict__ flags)
{
  __shared__ __align__(16) u8 smem[40960];   // 32KB staging + 8KB xbuf
  const int tid  = threadIdx.x;
  const int lane = tid & 63, wave = tid >> 6;
  const int wg   = blockIdx.x;
  const int mrow = lane & 15;
  const int m4   = (lane >> 4) * 4;
  const int q16  = (lane >> 4) * 16;
  const int swm  = (mrow & 7) << 4;

  if (wg < 32) {
    // ===== layer 0: wave owns 16 cols x 4 gates, K=512; per-wave flag =====
    const int grp = wg >> 3, wgi = wg & 7;
    int* fgrp = flags + grp*64;
    const int jc = (wgi*4 + wave) * 16;
    const u16* wbase = W0p + (wgi*4 + wave) * 32768;
    half8 wa[4][16];
#pragma unroll
    for (int g = 0; g < 4; ++g)
#pragma unroll
      for (int ks = 0; ks < 16; ++ks)
        wa[g][ks] = *(const half8*)(wbase + (g*16 + mrow)*512 + ks*32 + (lane >> 4)*8);
    const int bg = grp*16 + mrow;   // global batch row
    float cs[4] = {0.f, 0.f, 0.f, 0.f};
    // prefetch t=0 gate-table values
    int p = pidx[bg];
    f32x4 tg[4];
#pragma unroll
    for (int g = 0; g < 4; ++g) tg[g] = *(const f32x4*)(T0 + p*2048 + jc + m4 + g*512);
    for (int t = 0; t < S_LEN; ++t) {
      poll(fgrp, lane, t, t - (NB0 - 1));
      __syncthreads();                 // prev-step ds_reads done; smem reusable
      const u16* hr = h0b + ((t + NB0 - 1) % NB0) * HS;   // h0[t-1]
      u16*       hw = h0b + (t % NB0) * HS;               // h0[t]
      // ---- linear staged copy: 16KB group slice -> LDS ----
      {
        const char* gs = (const char*)hr + grp*16384;
        u32x4 d0 = gload16(gs + tid*16);
        u32x4 d1 = gload16(gs + tid*16 + 4096);
        u32x4 d2 = gload16(gs + tid*16 + 8192);
        u32x4 d3 = gload16(gs + tid*16 + 12288);
        asm volatile("s_waitcnt vmcnt(0)" ::: "memory");
        __builtin_amdgcn_sched_barrier(0);
        *(u32x4*)(smem + tid*16        ) = d0;
        *(u32x4*)(smem + tid*16 +  4096) = d1;
        *(u32x4*)(smem + tid*16 +  8192) = d2;
        *(u32x4*)(smem + tid*16 + 12288) = d3;
      }
      __syncthreads();
      half8 bf[16];
#pragma unroll
      for (int ks = 0; ks < 16; ++ks)
        bf[ks] = *(const half8*)(smem + mrow*1024 + ((ks*64 + q16) ^ swm));
      f32x4 acc[4] = {{0,0,0,0},{0,0,0,0},{0,0,0,0},{0,0,0,0}};
#pragma unroll
      for (int ks = 0; ks < 16; ++ks)
#pragma unroll
        for (int g = 0; g < 4; ++g)
          acc[g] = MFMA16(wa[g][ks], bf[ks], acc[g]);
      float hv[4];
#pragma unroll
      for (int r = 0; r < 4; ++r) {
        float gi = acc[0][r] + tg[0][r];
        float gf = acc[1][r] + tg[1][r];
        float gg = acc[2][r] + tg[2][r];
        float go = acc[3][r] + tg[3][r];
        float cc = sigf(gf)*cs[r] + sigf(gi)*tanhf_(gg);
        cs[r] = cc;
        hv[r] = sigf(go)*tanhf_(cc);
      }
      // producer-side swizzled store, then per-wave flag right after drain
      store_h4((char*)hw + bg*1024 + (((jc + m4)*2) ^ ((bg & 7) << 4)), hv);
      asm volatile("s_waitcnt vmcnt(0)" ::: "memory");
      if (lane == 0) store_flag(fgrp + wgi*4 + wave, t + 1);
      // T0 prefetch AFTER the flag (off critical path; completes during next poll)
      if (t + 1 < S_LEN) {
        int pn = pidx[(t+1)*64 + bg];
#pragma unroll
        for (int g = 0; g < 4; ++g)
          tg[g] = *(const f32x4*)(T0 + pn*2048 + jc + m4 + g*512);
      }
      // loop-carried pin: weights stay on-chip
#pragma unroll
      for (int g = 0; g < 4; ++g)
#pragma unroll
        for (int ks = 0; ks < 16; ++ks)
          asm volatile("" : "+v"(wa[g][ks]));
    }
  } else {
    // ===== layer 1: wave = (ch, kh); kh0 waves finish + publish per-wave flag =====
    const int w1 = wg - 32;
    const int grp = w1 >> 4, wgi = w1 & 15;
    int* fgrp = flags + grp*64;
    const int kh = wave & 1, ch = wave >> 1;
    const int jc = wgi*32 + ch*16;
    const u16* wbase = W1p + ((wgi*2 + ch)*2 + kh) * 32768;
    half8 wa[4][16];
#pragma unroll
    for (int g = 0; g < 4; ++g)
#pragma unroll
      for (int ks = 0; ks < 16; ++ks)
        wa[g][ks] = *(const half8*)(wbase + (g*16 + mrow)*512 + ks*32 + (lane >> 4)*8);
    const int bg = grp*16 + mrow;
    f32x4* xbuf = (f32x4*)(smem + 32768);
    f32x4 big[4];
#pragma unroll
    for (int g = 0; g < 4; ++g) big[g] = *(const f32x4*)(b1 + g*512 + jc + m4);
    const int shalf = tid >> 7;          // 0: stage h0 slice, 1: stage h1 slice
    const int sidx  = tid & 127;
    float cs[4] = {0.f, 0.f, 0.f, 0.f};
    for (int w = 1; w <= S_LEN; ++w) {
      const int u = w - 1;               // computing h1[u]
      poll(fgrp, lane, w, w - 1);
      __syncthreads();
      const u16* h0s = h0b + (u % NB0) * HS;               // h0[u]
      const u16* h1s = h1b + ((u + NB1 - 1) % NB1) * HS;   // h1[u-1]
      u16* hw = h1b + (u % NB1) * HS;                      // h1[u]
      {
        const char* gs = (const char*)(shalf ? h1s : h0s) + grp*16384;
        char* ls = (char*)smem + shalf*16384;
        u32x4 d[8];
#pragma unroll
        for (int j = 0; j < 8; ++j) d[j] = gload16(gs + sidx*16 + j*2048);
        asm volatile("s_waitcnt vmcnt(0)" ::: "memory");
        __builtin_amdgcn_sched_barrier(0);
#pragma unroll
        for (int j = 0; j < 8; ++j) *(u32x4*)(ls + sidx*16 + j*2048) = d[j];
      }
      __syncthreads();
      const char* lsrc = (const char*)smem + kh*16384;
      half8 bf[16];
#pragma unroll
      for (int ks = 0; ks < 16; ++ks)
        bf[ks] = *(const half8*)(lsrc + mrow*1024 + ((ks*64 + q16) ^ swm));
      f32x4 acc[4] = {{0,0,0,0},{0,0,0,0},{0,0,0,0},{0,0,0,0}};
#pragma unroll
      for (int ks = 0; ks < 16; ++ks)
#pragma unroll
        for (int g = 0; g < 4; ++g)
          acc[g] = MFMA16(wa[g][ks], bf[ks], acc[g]);
      if (kh == 1) {
#pragma unroll
        for (int g = 0; g < 4; ++g)
          xbuf[(ch*4 + g)*64 + lane] = acc[g];
      }
      __syncthreads();
      if (kh == 0) {
#pragma unroll
        for (int g = 0; g < 4; ++g)
          acc[g] += xbuf[(ch*4 + g)*64 + lane];
        float hv[4];
#pragma unroll
        for (int r = 0; r < 4; ++r) {
          float gi = acc[0][r] + big[0][r];
          float gf = acc[1][r] + big[1][r];
          float gg = acc[2][r] + big[2][r];
          float go = acc[3][r] + big[3][r];
          float cc = sigf(gf)*cs[r] + sigf(gi)*tanhf_(gg);
          cs[r] = cc;
          hv[r] = sigf(go)*tanhf_(cc);
        }
        store_h4((char*)hw + bg*1024 + (((jc + m4)*2) ^ ((bg & 7) << 4)), hv);
        asm volatile("s_waitcnt vmcnt(0)" ::: "memory");
        if (lane == 0) store_flag(fgrp + 32 + wgi*2 + ch, w);
      }
#pragma unroll
      for (int g = 0; g < 4; ++g)
#pragma unroll
        for (int ks = 0; ks < 16; ++ks)
          asm volatile("" : "+v"(wa[g][ks]));
    }
  }
}

// ---------- finalize: LayerNorm + projection from h1[2047] (fp16, swizzled rows) ----------
__global__ __launch_bounds__(256) void k_final(
    const u16* __restrict__ h1last, const float* __restrict__ ln_g,
    const float* __restrict__ ln_b, const float* __restrict__ Wp,
    const float* __restrict__ bp, float* __restrict__ out)
{
  __shared__ float sb[8];
  __shared__ float sred[4];
  const int b = blockIdx.x, tid = threadIdx.x;
  const char* hrow = (const char*)h1last + b * 1024;
  const int sw = (b & 7) << 4;
  float v1 = (float)*(const _Float16*)(hrow + ((tid*2) ^ sw));
  float v2 = (float)*(const _Float16*)(hrow + (((tid + 256)*2) ^ sw));
  float s1 = v1 + v2, s2 = v1*v1 + v2*v2;
#pragma unroll
  for (int o = 32; o; o >>= 1) { s1 += __shfl_down(s1, o); s2 += __shfl_down(s2, o); }
  if ((tid & 63) == 0) { sb[tid >> 6] = s1; sb[4 + (tid >> 6)] = s2; }
  __syncthreads();
  float S1 = sb[0] + sb[1] + sb[2] + sb[3];
  float S2 = sb[4] + sb[5] + sb[6] + sb[7];
  float mu = S1 * (1.f/512.f);
  float var = S2 * (1.f/512.f) - mu*mu;
  float inv = rsqrtf(var + 1e-5f);
  float acc = ((v1 - mu)*inv*ln_g[tid]       + ln_b[tid])       * Wp[tid]
            + ((v2 - mu)*inv*ln_g[tid + 256] + ln_b[tid + 256]) * Wp[tid + 256];
#pragma unroll
  for (int o = 32; o; o >>= 1) acc += __shfl_down(acc, o);
  if ((tid & 63) == 0) sred[tid >> 6] = acc;
  __syncthreads();
  if (tid == 0) out[b] = sred[0] + sred[1] + sred[2] + sred[3] + bp[0];
}

extern "C" void kernel_launch(void* const* d_in, const int* in_sizes, int n_in,
                              void* d_out, int out_size, void* d_ws, size_t ws_size,
                              hipStream_t stream) {
  (void)in_sizes; (void)n_in; (void)out_size; (void)ws_size;
  const int*   inp   = (const int*)d_in[0];
  const float* embed = (const float*)d_in[1];
  const float* Wih   = (const float*)d_in[2];
  const float* Whh   = (const float*)d_in[3];
  const float* bih   = (const float*)d_in[4];
  const float* bhh   = (const float*)d_in[5];
  const float* ln_g  = (const float*)d_in[6];
  const float* ln_b  = (const float*)d_in[7];
  const float* Wp    = (const float*)d_in[8];
  const float* bp    = (const float*)d_in[9];
  float* out = (float*)d_out;
  char* ws = (char*)d_ws;

  u16*   W0p  = (u16*)  (ws + OFF_W0P);
  u16*   W1p  = (u16*)  (ws + OFF_W1P);
  float* T0   = (float*)(ws + OFF_T0);
  float* b1   = (float*)(ws + OFF_B1);
  u8*    pidx = (u8*)   (ws + OFF_PIDX);
  u16*   h0   = (u16*)  (ws + OFF_H0);
  u16*   h1   = (u16*)  (ws + OFF_H1);
  int*   flags= (int*)  (ws + OFF_FLAG);

  k_prep<<<512, 256, 0, stream>>>(Wih, Whh, bih, bhh, W0p, W1p, b1, h0, flags);
  k_pidx<<<64, 256, 0, stream>>>(inp, pidx);
  k_table<<<128, 256, 0, stream>>>(embed, Wih, bih, bhh, T0);

  k_lstm<<<dim3(96), dim3(256), 0, stream>>>(W0p, W1p, T0, b1, pidx, h0, h1, flags);

  // h1[2047] lives in buffer (2047 % 4) == 3
  k_final<<<64, 256, 0, stream>>>(h1 + 3*HS, ln_g, ln_b, Wp, bp, out);
}

// Round 10
// 9971.029 us; speedup vs baseline: 1.8156x; 1.0115x over previous
//
#include <hip/hip_runtime.h>

typedef unsigned short u16;
typedef unsigned char u8;
typedef unsigned long long u64;
typedef __attribute__((ext_vector_type(8))) _Float16 half8;
typedef __attribute__((ext_vector_type(4))) float f32x4;
typedef __attribute__((ext_vector_type(4))) unsigned int u32x4;

#define MFMA16(a,b,c) __builtin_amdgcn_mfma_f32_16x16x32_f16((a),(b),(c),0,0,0)

#define S_LEN 2048
#define HS (64*512)    // u16 elements per h buffer [64][512]
#define NB0 4
#define NB1 4
#define NGRP 4
#define NWGL 256
#define NACT 96        // 4 groups x (8 L0 + 16 L1)

// ---------- sync[] int indices ----------
#define SI_FLAGF   0      // fast flags: 4 grp x 32 (fA[0..7], fB[16..31])
#define SI_XCDPUB  256
#define SI_ROLETAB 512
#define SI_FAILED  1104
#define SI_SUCCESS 1120
#define SI_RUNSAFE 1136
#define SI_FLAGS   1200   // safe flags: 4 grp x 32
#define SI_TOTAL   1344

// ---------- ws layout (bytes) ----------
#define OFF_W0P  0
#define OFF_W1P  2097152
#define OFF_T0   6291456
#define OFF_B1   6422528
#define OFF_PIDX 6430720
#define OFF_H0   6561792
#define OFF_H1   6823936
#define OFF_SYNC 7086080

__device__ __forceinline__ u16 f2h(float f) {
  _Float16 h = (_Float16)f;
  return __builtin_bit_cast(u16, h);
}
__device__ __forceinline__ float sigf(float x)   { return 1.f/(1.f + __expf(-x)); }
__device__ __forceinline__ float tanhf_(float x) { return 2.f/(1.f + __expf(-2.f*x)) - 1.f; }

// ---- scalar coherent helpers ----
__device__ __forceinline__ int ld_sc01(const int* p) {
  int v; asm volatile("global_load_dword %0, %1, off sc0 sc1\ns_waitcnt vmcnt(0)"
                      : "=v"(v) : "v"(p) : "memory"); return v;
}
__device__ __forceinline__ void st_sc01(int* p, int v) {
  asm volatile("global_store_dword %0, %1, off sc0 sc1" :: "v"(p), "v"(v) : "memory");
}
__device__ __forceinline__ int ld_sc0(const int* p) {
  int v; asm volatile("global_load_dword %0, %1, off sc0\ns_waitcnt vmcnt(0)"
                      : "=v"(v) : "v"(p) : "memory"); return v;
}
__device__ __forceinline__ void st_sc0(int* p, int v) {
  asm volatile("global_store_dword %0, %1, off sc0" :: "v"(p), "v"(v) : "memory");
}

// ---- templated data-path ops: LOC -> XCD-L2 (sc0); !LOC -> device scope (sc0 sc1) ----
template<bool LOC> __device__ __forceinline__ u32x4 gld16(const void* p) {
  u32x4 d;
  if constexpr (LOC) asm volatile("global_load_dwordx4 %0, %1, off sc0" : "=&v"(d) : "v"(p) : "memory");
  else               asm volatile("global_load_dwordx4 %0, %1, off sc0 sc1" : "=&v"(d) : "v"(p) : "memory");
  return d;
}
template<bool LOC> __device__ __forceinline__ void sth4(void* p, const float* hv) {
  union { u64 q; _Float16 h[4]; } u;
  u.h[0] = (_Float16)hv[0]; u.h[1] = (_Float16)hv[1];
  u.h[2] = (_Float16)hv[2]; u.h[3] = (_Float16)hv[3];
  if constexpr (LOC) asm volatile("global_store_dwordx2 %0, %1, off sc0" :: "v"(p), "v"(u.q) : "memory");
  else               asm volatile("global_store_dwordx2 %0, %1, off sc0 sc1" :: "v"(p), "v"(u.q) : "memory");
}
template<bool LOC> __device__ __forceinline__ void stflag(int* p, int v) {
  if constexpr (LOC) st_sc0(p, v); else st_sc01(p, v);
}
// capped wave0 poll with backoff: lanes 0..15 -> fA[lane&7] >= nA, 16..31 -> fB[lane-16] >= nB
template<bool LOC> __device__ __forceinline__ bool pollc(const int* fgrp, const int* failed,
                                                         int lane, int nA, int nB) {
  const int idx = lane & 31;
  const int* p = fgrp + ((idx < 16) ? (idx & 7) : idx);
  const int need = (idx < 16) ? nA : nB;
  for (int outer = 0; outer < 512; ++outer) {
    for (int inner = 0; inner < 8; ++inner) {
      int v = LOC ? ld_sc0(p) : ld_sc01(p);
      if (__all(v >= need)) return true;
      __builtin_amdgcn_s_sleep(4);   // backoff: keep flag lines cool (R3/R8 lesson)
    }
    if (ld_sc01(failed)) return false;
  }
  return false;   // ~1.5 ms cap
}
// uncapped wave0 poll with backoff (safe path; monotonic flags + guaranteed producers)
__device__ __forceinline__ void poll_s(const int* fgrp, int lane, int nA, int nB) {
  const int idx = lane & 31;
  const int* p = fgrp + ((idx < 16) ? (idx & 7) : idx);
  const int need = (idx < 16) ? nA : nB;
  for (;;) {
    int v = ld_sc01(p);
    if (__all(v >= need)) break;
    __builtin_amdgcn_s_sleep(4);
  }
}

// ---------- prep ----------
__global__ void k_prep(const float* __restrict__ Wih, const float* __restrict__ Whh,
                       const float* __restrict__ bih, const float* __restrict__ bhh,
                       u16* __restrict__ W0p, u16* __restrict__ W1p,
                       float* __restrict__ b1, u16* __restrict__ hz, int* __restrict__ sync)
{
  int i = blockIdx.x * blockDim.x + threadIdx.x;
  int st = gridDim.x * blockDim.x;
  for (int e = i; e < 8*4*4*16*512; e += st) {
    int k = e & 511, m = (e >> 9) & 15, g = (e >> 13) & 3, wv = (e >> 15) & 3, wgi = e >> 17;
    int row = g*512 + (wgi*4 + wv)*16 + m;
    W0p[e] = f2h(Whh[row*512 + k]);
  }
  for (int e = i; e < 16*2*2*4*16*512; e += st) {
    int k = e & 511, m = (e >> 9) & 15, g = (e >> 13) & 3, kh = (e >> 15) & 1,
        ch = (e >> 16) & 1, wgi = e >> 17;
    int row = g*512 + wgi*32 + ch*16 + m;
    const float* src = kh ? Whh : Wih;
    W1p[e] = f2h(src[2048*512 + row*512 + k]);
  }
  for (int e = i; e < 4*512; e += st) b1[e] = bih[2048 + e] + bhh[2048 + e];
  for (int e = i; e < (NB0 + NB1)*HS; e += st) hz[e] = 0;
  for (int e = i; e < SI_TOTAL; e += st) sync[e] = 0;
}

// ---------- pidx ----------
__global__ void k_pidx(const int* __restrict__ inp32, u8* __restrict__ pidx)
{
  __shared__ int is64s;
  if (threadIdx.x == 0) {
    int z = 0;
    for (int t = 0; t < 64; ++t) z |= inp32[2*t + 1];
    is64s = (z == 0) ? 1 : 0;
  }
  __syncthreads();
  const int is64 = is64s;
  int i = blockIdx.x * blockDim.x + threadIdx.x;
  int st = gridDim.x * blockDim.x;
  for (int e = i; e < S_LEN*64; e += st) {
    int t = e >> 6, b = e & 63;
    int i0 = b * S_LEN + t;
    int i1 = 64 * S_LEN + b * S_LEN + t;
    int a = is64 ? inp32[2*i0] : inp32[i0];
    int c = is64 ? inp32[2*i1] : inp32[i1];
    pidx[e] = (u8)(a * 4 + c);
  }
}

// ---------- table ----------
__global__ void k_table(const float* __restrict__ embed, const float* __restrict__ Wih,
                        const float* __restrict__ bih, const float* __restrict__ bhh,
                        float* __restrict__ T0)
{
  int idx = blockIdx.x * blockDim.x + threadIdx.x;
  if (idx >= 16*2048) return;
  int p = idx >> 11, gj = idx & 2047;
  const float* ea = embed + (p >> 2) * 512;
  const float* ec = embed + (p & 3) * 512;
  const float* w  = Wih + gj * 512;
  float acc = bih[gj] + bhh[gj];
  for (int k = 0; k < 512; ++k) acc += (ea[k] + ec[k]) * w[k];
  T0[p * 2048 + gj] = acc;
}

// ================= fast-kernel layer bodies (capped, abortable) =================
template<bool LOC>
__device__ bool l0_fast(const u16* __restrict__ W0p, const float* __restrict__ T0,
                        const u8* __restrict__ pidx, u16* __restrict__ h0b,
                        int* fgrp, int* failed, u8* smem, int* s_okv, int grp, int wgi)
{
  const int tid = threadIdx.x;
  const int lane = tid & 63, wave = tid >> 6;
  const int mrow = lane & 15;
  const int m4 = (lane >> 4) * 4;
  const int q16 = (lane >> 4) * 16;
  const int swm = (mrow & 7) << 4;
  const int jc = (wgi*4 + wave) * 16;
  const u16* wbase = W0p + (wgi*4 + wave) * 32768;
  half8 wa[4][16];
#pragma unroll
  for (int g = 0; g < 4; ++g)
#pragma unroll
    for (int ks = 0; ks < 16; ++ks)
      wa[g][ks] = *(const half8*)(wbase + (g*16 + mrow)*512 + ks*32 + (lane >> 4)*8);
  const int bg = grp*16 + mrow;
  float cs[4] = {0.f, 0.f, 0.f, 0.f};
  int p = pidx[bg];
  f32x4 tg[4];
#pragma unroll
  for (int g = 0; g < 4; ++g) tg[g] = *(const f32x4*)(T0 + p*2048 + jc + m4 + g*512);
  for (int t = 0; t < S_LEN; ++t) {
    if (wave == 0) {
      bool ok = pollc<LOC>(fgrp, failed, lane, t, t - (NB0 - 1));
      if (lane == 0) *s_okv = ok ? 1 : 0;
    }
    __syncthreads();
    if (!*s_okv) { if (tid == 0) st_sc01(failed, 1); return false; }
    const u16* hr = h0b + ((t + NB0 - 1) % NB0) * HS;
    u16*       hw = h0b + (t % NB0) * HS;
    {
      const char* gs = (const char*)hr + grp*16384;
      u32x4 d0 = gld16<LOC>(gs + tid*16);
      u32x4 d1 = gld16<LOC>(gs + tid*16 + 4096);
      u32x4 d2 = gld16<LOC>(gs + tid*16 + 8192);
      u32x4 d3 = gld16<LOC>(gs + tid*16 + 12288);
      asm volatile("s_waitcnt vmcnt(0)" ::: "memory");
      __builtin_amdgcn_sched_barrier(0);
      *(u32x4*)(smem + tid*16        ) = d0;
      *(u32x4*)(smem + tid*16 +  4096) = d1;
      *(u32x4*)(smem + tid*16 +  8192) = d2;
      *(u32x4*)(smem + tid*16 + 12288) = d3;
    }
    __syncthreads();
    half8 bf[16];
#pragma unroll
    for (int ks = 0; ks < 16; ++ks)
      bf[ks] = *(const half8*)(smem + mrow*1024 + ((ks*64 + q16) ^ swm));
    f32x4 acc[4] = {{0,0,0,0},{0,0,0,0},{0,0,0,0},{0,0,0,0}};
#pragma unroll
    for (int ks = 0; ks < 16; ++ks)
#pragma unroll
      for (int g = 0; g < 4; ++g)
        acc[g] = MFMA16(wa[g][ks], bf[ks], acc[g]);
    float hv[4];
#pragma unroll
    for (int r = 0; r < 4; ++r) {
      float gi = acc[0][r] + tg[0][r];
      float gf = acc[1][r] + tg[1][r];
      float gg = acc[2][r] + tg[2][r];
      float go = acc[3][r] + tg[3][r];
      float cc = sigf(gf)*cs[r] + sigf(gi)*tanhf_(gg);
      cs[r] = cc;
      hv[r] = sigf(go)*tanhf_(cc);
    }
    sth4<LOC>((char*)hw + bg*1024 + (((jc + m4)*2) ^ ((bg & 7) << 4)), hv);
    asm volatile("s_waitcnt vmcnt(0)" ::: "memory");
    __syncthreads();
    if (tid == 0) stflag<LOC>(fgrp + wgi, t + 1);
    if (t + 1 < S_LEN) {
      int pn = pidx[(t+1)*64 + bg];
#pragma unroll
      for (int g = 0; g < 4; ++g)
        tg[g] = *(const f32x4*)(T0 + pn*2048 + jc + m4 + g*512);
    }
#pragma unroll
    for (int g = 0; g < 4; ++g)
#pragma unroll
      for (int ks = 0; ks < 16; ++ks)
        asm volatile("" : "+v"(wa[g][ks]));
  }
  return true;
}

template<bool LOC>
__device__ bool l1_fast(const u16* __restrict__ W1p, const float* __restrict__ b1,
                        u16* __restrict__ h0b, u16* __restrict__ h1b,
                        int* fgrp, int* failed, u8* smem, int* s_okv, int grp, int wgi)
{
  const int tid = threadIdx.x;
  const int lane = tid & 63, wave = tid >> 6;
  const int mrow = lane & 15;
  const int m4 = (lane >> 4) * 4;
  const int q16 = (lane >> 4) * 16;
  const int swm = (mrow & 7) << 4;
  const int kh = wave & 1, ch = wave >> 1;
  const int jc = wgi*32 + ch*16;
  const u16* wbase = W1p + ((wgi*2 + ch)*2 + kh) * 32768;
  half8 wa[4][16];
#pragma unroll
  for (int g = 0; g < 4; ++g)
#pragma unroll
    for (int ks = 0; ks < 16; ++ks)
      wa[g][ks] = *(const half8*)(wbase + (g*16 + mrow)*512 + ks*32 + (lane >> 4)*8);
  const int bg = grp*16 + mrow;
  f32x4* xbuf = (f32x4*)(smem + 32768);
  f32x4 big[4];
#pragma unroll
  for (int g = 0; g < 4; ++g) big[g] = *(const f32x4*)(b1 + g*512 + jc + m4);
  const int shalf = tid >> 7;
  const int sidx  = tid & 127;
  float cs[4] = {0.f, 0.f, 0.f, 0.f};
  for (int w = 1; w <= S_LEN; ++w) {
    const int u = w - 1;
    if (wave == 0) {
      bool ok = pollc<LOC>(fgrp, failed, lane, w, w - 1);
      if (lane == 0) *s_okv = ok ? 1 : 0;
    }
    __syncthreads();
    if (!*s_okv) { if (tid == 0) st_sc01(failed, 1); return false; }
    const u16* h0s = h0b + (u % NB0) * HS;
    const u16* h1s = h1b + ((u + NB1 - 1) % NB1) * HS;
    u16* hw = h1b + (u % NB1) * HS;
    {
      const char* gs = (const char*)(shalf ? h1s : h0s) + grp*16384;
      char* ls = (char*)smem + shalf*16384;
      u32x4 d[8];
#pragma unroll
      for (int j = 0; j < 8; ++j) d[j] = gld16<LOC>(gs + sidx*16 + j*2048);
      asm volatile("s_waitcnt vmcnt(0)" ::: "memory");
      __builtin_amdgcn_sched_barrier(0);
#pragma unroll
      for (int j = 0; j < 8; ++j) *(u32x4*)(ls + sidx*16 + j*2048) = d[j];
    }
    __syncthreads();
    const char* lsrc = (const char*)smem + kh*16384;
    half8 bf[16];
#pragma unroll
    for (int ks = 0; ks < 16; ++ks)
      bf[ks] = *(const half8*)(lsrc + mrow*1024 + ((ks*64 + q16) ^ swm));
    f32x4 acc[4] = {{0,0,0,0},{0,0,0,0},{0,0,0,0},{0,0,0,0}};
#pragma unroll
    for (int ks = 0; ks < 16; ++ks)
#pragma unroll
      for (int g = 0; g < 4; ++g)
        acc[g] = MFMA16(wa[g][ks], bf[ks], acc[g]);
    if (kh == 1) {
#pragma unroll
      for (int g = 0; g < 4; ++g)
        xbuf[(ch*4 + g)*64 + lane] = acc[g];
    }
    __syncthreads();
    if (kh == 0) {
#pragma unroll
      for (int g = 0; g < 4; ++g)
        acc[g] += xbuf[(ch*4 + g)*64 + lane];
      float hv[4];
#pragma unroll
      for (int r = 0; r < 4; ++r) {
        float gi = acc[0][r] + big[0][r];
        float gf = acc[1][r] + big[1][r];
        float gg = acc[2][r] + big[2][r];
        float go = acc[3][r] + big[3][r];
        float cc = sigf(gf)*cs[r] + sigf(gi)*tanhf_(gg);
        cs[r] = cc;
        hv[r] = sigf(go)*tanhf_(cc);
      }
      sth4<LOC>((char*)hw + bg*1024 + (((jc + m4)*2) ^ ((bg & 7) << 4)), hv);
    }
    asm volatile("s_waitcnt vmcnt(0)" ::: "memory");
    __syncthreads();
    if (tid == 0) stflag<LOC>(fgrp + 16 + wgi, w);
#pragma unroll
    for (int g = 0; g < 4; ++g)
#pragma unroll
      for (int ks = 0; ks < 16; ++ks)
        asm volatile("" : "+v"(wa[g][ks]));
  }
  return true;
}

// ---------- fast kernel: capped discovery + XCD-local loop + success counting ----------
__global__ __launch_bounds__(256, 1) void k_fast(
    const u16* __restrict__ W0p, const u16* __restrict__ W1p,
    const float* __restrict__ T0, const float* __restrict__ b1,
    const u8* __restrict__ pidx,
    u16* __restrict__ h0b, u16* __restrict__ h1b, int* __restrict__ sync)
{
  __shared__ __align__(16) u8 smem[40960];
  __shared__ int sinfo;
  __shared__ int s_okv;
  const int tid = threadIdx.x, bid = blockIdx.x;
  int* flags   = sync + SI_FLAGF;
  int* xcdpub  = sync + SI_XCDPUB;
  int* roleTab = sync + SI_ROLETAB;
  int* failed  = sync + SI_FAILED;
  int* succ    = sync + SI_SUCCESS;

  // phase 1: publish XCD id (unconditional)
  if (tid == 0) {
    int xcd;
    asm volatile("s_getreg_b32 %0, hwreg(HW_REG_XCC_ID)" : "=s"(xcd));
    st_sc01(xcdpub + bid, (xcd & 7) + 1);
  }
  // phase 2: coordinator assigns (all waits capped, with backoff)
  if (bid == 0) {
    int* lmap = (int*)smem;
    for (int i = tid; i < NWGL; i += 256) {
      int v = 0;
      for (int it = 0; it < 4000 && v == 0; ++it) {
        v = ld_sc01(xcdpub + i);
        if (v == 0) __builtin_amdgcn_s_sleep(2);
      }
      lmap[i] = v - 1;   // -1 if never seen
    }
    __syncthreads();
    if (tid == 0) {
      int cnt[8] = {0,0,0,0,0,0,0,0};
      for (int i = 0; i < NWGL; ++i) { int x = lmap[i]; if (x >= 0 && x < 8) cnt[x]++; }
      int gx[NGRP], gl[NGRP], used = 0;
      for (int g = 0; g < NGRP; ++g) {
        int best = 0, bc = -1;
        for (int x = 0; x < 8; ++x)
          if (!((used >> x) & 1) && cnt[x] > bc) { bc = cnt[x]; best = x; }
        gx[g] = best; used |= 1 << best;
        gl[g] = (bc >= 24) ? 1 : 0;
      }
      int rc[NGRP] = {0,0,0,0};
      for (int i = 0; i < NWGL; ++i) {
        int x = lmap[i], as = 1;
        if (x >= 0 && x < 8)
          for (int g = 0; g < NGRP; ++g)
            if (gl[g] && gx[g] == x && rc[g] < 24) {
              as = (1 << 30) | (g << 16) | (rc[g] << 8) | 1; rc[g]++; break;
            }
        lmap[i] = as;
      }
      for (int g = 0; g < NGRP; ++g)
        if (!gl[g])
          for (int i = 0; i < NWGL && rc[g] < 24; ++i)
            if (lmap[i] == 1) { lmap[i] = (1 << 30) | (g << 16) | (rc[g] << 8); rc[g]++; }
      if (rc[0] + rc[1] + rc[2] + rc[3] != NACT) {
        for (int i = 0; i < NWGL; ++i) lmap[i] = 1;   // abort -> all surplus
        st_sc01(failed, 1);
      }
      for (int i = 0; i < NWGL; ++i) st_sc01(roleTab + i, lmap[i]);
    }
    __syncthreads();
  }
  // phase 3: read my assignment (capped; coordinator always writes)
  if (tid == 0) {
    int v = 0;
    for (int it = 0; it < 20000 && v == 0; ++it) {
      v = ld_sc01(roleTab + bid);
      if (v == 0) __builtin_amdgcn_s_sleep(4);
    }
    if (v == 0) st_sc01(failed, 1);
    sinfo = v;
  }
  __syncthreads();
  const int info = sinfo;
  if (!(info & (1 << 30))) return;   // surplus or cap
  const int grp = (info >> 16) & 0xff, role = (info >> 8) & 0xff;
  const int loc = info & 1;

  int* fgrp = flags + grp * 32;
  bool done;
  if (role < 8) {
    done = loc ? l0_fast<true >(W0p, T0, pidx, h0b, fgrp, failed, smem, &s_okv, grp, role)
               : l0_fast<false>(W0p, T0, pidx, h0b, fgrp, failed, smem, &s_okv, grp, role);
  } else {
    done = loc ? l1_fast<true >(W1p, b1, h0b, h1b, fgrp, failed, smem, &s_okv, grp, role - 8)
               : l1_fast<false>(W1p, b1, h0b, h1b, fgrp, failed, smem, &s_okv, grp, role - 8);
  }
  if (done && tid == 0)
    __hip_atomic_fetch_add(succ, 1, __ATOMIC_RELAXED, __HIP_MEMORY_SCOPE_AGENT);
}

// ---------- check: arm safe path + re-zero h rings if fast failed ----------
__global__ __launch_bounds__(256) void k_check(int* __restrict__ sync, u64* __restrict__ hz)
{
  const int i = blockIdx.x * blockDim.x + threadIdx.x;
  const int st = gridDim.x * blockDim.x;
  const int s = sync[SI_SUCCESS];
  if (i == 0) sync[SI_RUNSAFE] = (s == NACT) ? 0 : 1;
  if (s != NACT) {
    for (int e = i; e < (NB0 + NB1) * HS / 4; e += st) hz[e] = 0;
  }
}

// ---------- safe kernel: proven device-scope loop (wave0 poll + backoff) ----------
__device__ __forceinline__ u32x4 gload16_s(const void* p) {
  u32x4 d;
  asm volatile("global_load_dwordx4 %0, %1, off sc0 sc1"
               : "=&v"(d) : "v"(p) : "memory");
  return d;
}
__device__ __forceinline__ void store_h4_s(u16* p, const float* hv) {
  union { u64 q; _Float16 h[4]; } u;
  u.h[0] = (_Float16)hv[0]; u.h[1] = (_Float16)hv[1];
  u.h[2] = (_Float16)hv[2]; u.h[3] = (_Float16)hv[3];
  __hip_atomic_store((u64*)p, u.q, __ATOMIC_RELAXED, __HIP_MEMORY_SCOPE_AGENT);
}

__global__ __launch_bounds__(256, 1) void k_safe(
    const u16* __restrict__ W0p, const u16* __restrict__ W1p,
    const float* __restrict__ T0, const float* __restrict__ b1,
    const u8* __restrict__ pidx,
    u16* __restrict__ h0b, u16* __restrict__ h1b, int* __restrict__ sync)
{
  __shared__ __align__(16) u8 smem[40960];
  __shared__ int sgo;
  const int tid  = threadIdx.x;
  if (tid == 0) sgo = sync[SI_RUNSAFE];
  __syncthreads();
  if (!sgo) return;
  int* flags = sync + SI_FLAGS;

  const int lane = tid & 63, wave = tid >> 6;
  const int wg   = blockIdx.x;
  const int mrow = lane & 15;
  const int m4   = (lane >> 4) * 4;
  const int q16  = (lane >> 4) * 16;
  const int swm  = (mrow & 7) << 4;

  if (wg < 32) {
    const int grp = wg >> 3, wgi = wg & 7;
    int* fgrp = flags + grp*32;
    const int jc = (wgi*4 + wave) * 16;
    const u16* wbase = W0p + (wgi*4 + wave) * 32768;
    half8 wa[4][16];
#pragma unroll
    for (int g = 0; g < 4; ++g)
#pragma unroll
      for (int ks = 0; ks < 16; ++ks)
        wa[g][ks] = *(const half8*)(wbase + (g*16 + mrow)*512 + ks*32 + (lane >> 4)*8);
    const int bg = grp*16 + mrow;
    float cs[4] = {0.f, 0.f, 0.f, 0.f};
    int p = pidx[bg];
    f32x4 tg[4];
#pragma unroll
    for (int g = 0; g < 4; ++g) tg[g] = *(const f32x4*)(T0 + p*2048 + jc + m4 + g*512);
    for (int t = 0; t < S_LEN; ++t) {
      if (wave == 0) poll_s(fgrp, lane, t, t - (NB0 - 1));
      __syncthreads();
      const u16* hr = h0b + ((t + NB0 - 1) % NB0) * HS;
      u16*       hw = h0b + (t % NB0) * HS;
      {
        const char* gs = (const char*)hr + grp*16384;
        u32x4 d0 = gload16_s(gs + tid*16);
        u32x4 d1 = gload16_s(gs + tid*16 + 4096);
        u32x4 d2 = gload16_s(gs + tid*16 + 8192);
        u32x4 d3 = gload16_s(gs + tid*16 + 12288);
        asm volatile("s_waitcnt vmcnt(0)" ::: "memory");
        __builtin_amdgcn_sched_barrier(0);
        *(u32x4*)(smem + tid*16        ) = d0;
        *(u32x4*)(smem + tid*16 +  4096) = d1;
        *(u32x4*)(smem + tid*16 +  8192) = d2;
        *(u32x4*)(smem + tid*16 + 12288) = d3;
      }
      __syncthreads();
      half8 bf[16];
#pragma unroll
      for (int ks = 0; ks < 16; ++ks)
        bf[ks] = *(const half8*)(smem + mrow*1024 + ((ks*64 + q16) ^ swm));
      f32x4 acc[4] = {{0,0,0,0},{0,0,0,0},{0,0,0,0},{0,0,0,0}};
#pragma unroll
      for (int ks = 0; ks < 16; ++ks)
#pragma unroll
        for (int g = 0; g < 4; ++g)
          acc[g] = MFMA16(wa[g][ks], bf[ks], acc[g]);
      float hv[4];
#pragma unroll
      for (int r = 0; r < 4; ++r) {
        float gi = acc[0][r] + tg[0][r];
        float gf = acc[1][r] + tg[1][r];
        float gg = acc[2][r] + tg[2][r];
        float go = acc[3][r] + tg[3][r];
        float cc = sigf(gf)*cs[r] + sigf(gi)*tanhf_(gg);
        cs[r] = cc;
        hv[r] = sigf(go)*tanhf_(cc);
      }
      store_h4_s((u16*)((char*)hw + bg*1024 + (((jc + m4)*2) ^ ((bg & 7) << 4))), hv);
      asm volatile("s_waitcnt vmcnt(0)" ::: "memory");
      __syncthreads();
      if (tid == 0) st_sc01(fgrp + wgi, t + 1);
      if (t + 1 < S_LEN) {
        int pn = pidx[(t+1)*64 + bg];
#pragma unroll
        for (int g = 0; g < 4; ++g)
          tg[g] = *(const f32x4*)(T0 + pn*2048 + jc + m4 + g*512);
      }
#pragma unroll
      for (int g = 0; g < 4; ++g)
#pragma unroll
        for (int ks = 0; ks < 16; ++ks)
          asm volatile("" : "+v"(wa[g][ks]));
    }
  } else {
    const int w1 = wg - 32;
    const int grp = w1 >> 4, wgi = w1 & 15;
    int* fgrp = flags + grp*32;
    const int kh = wave & 1, ch = wave >> 1;
    const int jc = wgi*32 + ch*16;
    const u16* wbase = W1p + ((wgi*2 + ch)*2 + kh) * 32768;
    half8 wa[4][16];
#pragma unroll
    for (int g = 0; g < 4; ++g)
#pragma unroll
      for (int ks = 0; ks < 16; ++ks)
        wa[g][ks] = *(const half8*)(wbase + (g*16 + mrow)*512 + ks*32 + (lane >> 4)*8);
    const int bg = grp*16 + mrow;
    f32x4* xbuf = (f32x4*)(smem + 32768);
    f32x4 big[4];
#pragma unroll
    for (int g = 0; g < 4; ++g) big[g] = *(const f32x4*)(b1 + g*512 + jc + m4);
    const int shalf = tid >> 7;
    const int sidx  = tid & 127;
    float cs[4] = {0.f, 0.f, 0.f, 0.f};
    for (int w = 1; w <= S_LEN; ++w) {
      const int u = w - 1;
      if (wave == 0) poll_s(fgrp, lane, w, w - 1);
      __syncthreads();
      const u16* h0s = h0b + (u % NB0) * HS;
      const u16* h1s = h1b + ((u + NB1 - 1) % NB1) * HS;
      u16* hw = h1b + (u % NB1) * HS;
      {
        const char* gs = (const char*)(shalf ? h1s : h0s) + grp*16384;
        char* ls = (char*)smem + shalf*16384;
        u32x4 d[8];
#pragma unroll
        for (int j = 0; j < 8; ++j) d[j] = gload16_s(gs + sidx*16 + j*2048);
        asm volatile("s_waitcnt vmcnt(0)" ::: "memory");
        __builtin_amdgcn_sched_barrier(0);
#pragma unroll
        for (int j = 0; j < 8; ++j) *(u32x4*)(ls + sidx*16 + j*2048) = d[j];
      }
      __syncthreads();
      const char* lsrc = (const char*)smem + kh*16384;
      half8 bf[16];
#pragma unroll
      for (int ks = 0; ks < 16; ++ks)
        bf[ks] = *(const half8*)(lsrc + mrow*1024 + ((ks*64 + q16) ^ swm));
      f32x4 acc[4] = {{0,0,0,0},{0,0,0,0},{0,0,0,0},{0,0,0,0}};
#pragma unroll
      for (int ks = 0; ks < 16; ++ks)
#pragma unroll
        for (int g = 0; g < 4; ++g)
          acc[g] = MFMA16(wa[g][ks], bf[ks], acc[g]);
      if (kh == 1) {
#pragma unroll
        for (int g = 0; g < 4; ++g)
          xbuf[(ch*4 + g)*64 + lane] = acc[g];
      }
      __syncthreads();
      if (kh == 0) {
#pragma unroll
        for (int g = 0; g < 4; ++g)
          acc[g] += xbuf[(ch*4 + g)*64 + lane];
        float hv[4];
#pragma unroll
        for (int r = 0; r < 4; ++r) {
          float gi = acc[0][r] + big[0][r];
          float gf = acc[1][r] + big[1][r];
          float gg = acc[2][r] + big[2][r];
          float go = acc[3][r] + big[3][r];
          float cc = sigf(gf)*cs[r] + sigf(gi)*tanhf_(gg);
          cs[r] = cc;
          hv[r] = sigf(go)*tanhf_(cc);
        }
        store_h4_s((u16*)((char*)hw + bg*1024 + (((jc + m4)*2) ^ ((bg & 7) << 4))), hv);
      }
      asm volatile("s_waitcnt vmcnt(0)" ::: "memory");
      __syncthreads();
      if (tid == 0) st_sc01(fgrp + 16 + wgi, w);
#pragma unroll
      for (int g = 0; g < 4; ++g)
#pragma unroll
        for (int ks = 0; ks < 16; ++ks)
          asm volatile("" : "+v"(wa[g][ks]));
    }
  }
}

// ---------- finalize: LayerNorm + projection from h1[2047] (fp16, swizzled rows) ----------
__global__ __launch_bounds__(256) void k_final(
    const u16* __restrict__ h1last, const float* __restrict__ ln_g,
    const float* __restrict__ ln_b, const float* __restrict__ Wp,
    const float* __restrict__ bp, float* __restrict__ out)
{
  __shared__ float sb[8];
  __shared__ float sred[4];
  const int b = blockIdx.x, tid = threadIdx.x;
  const char* hrow = (const char*)h1last + b * 1024;
  const int sw = (b & 7) << 4;
  float v1 = (float)*(const _Float16*)(hrow + ((tid*2) ^ sw));
  float v2 = (float)*(const _Float16*)(hrow + (((tid + 256)*2) ^ sw));
  float s1 = v1 + v2, s2 = v1*v1 + v2*v2;
#pragma unroll
  for (int o = 32; o; o >>= 1) { s1 += __shfl_down(s1, o); s2 += __shfl_down(s2, o); }
  if ((tid & 63) == 0) { sb[tid >> 6] = s1; sb[4 + (tid >> 6)] = s2; }
  __syncthreads();
  float S1 = sb[0] + sb[1] + sb[2] + sb[3];
  float S2 = sb[4] + sb[5] + sb[6] + sb[7];
  float mu = S1 * (1.f/512.f);
  float var = S2 * (1.f/512.f) - mu*mu;
  float inv = rsqrtf(var + 1e-5f);
  float acc = ((v1 - mu)*inv*ln_g[tid]       + ln_b[tid])       * Wp[tid]
            + ((v2 - mu)*inv*ln_g[tid + 256] + ln_b[tid + 256]) * Wp[tid + 256];
#pragma unroll
  for (int o = 32; o; o >>= 1) acc += __shfl_down(acc, o);
  if ((tid & 63) == 0) sred[tid >> 6] = acc;
  __syncthreads();
  if (tid == 0) out[b] = sred[0] + sred[1] + sred[2] + sred[3] + bp[0];
}

extern "C" void kernel_launch(void* const* d_in, const int* in_sizes, int n_in,
                              void* d_out, int out_size, void* d_ws, size_t ws_size,
                              hipStream_t stream) {
  (void)in_sizes; (void)n_in; (void)out_size; (void)ws_size;
  const int*   inp   = (const int*)d_in[0];
  const float* embed = (const float*)d_in[1];
  const float* Wih   = (const float*)d_in[2];
  const float* Whh   = (const float*)d_in[3];
  const float* bih   = (const float*)d_in[4];
  const float* bhh   = (const float*)d_in[5];
  const float* ln_g  = (const float*)d_in[6];
  const float* ln_b  = (const float*)d_in[7];
  const float* Wp    = (const float*)d_in[8];
  const float* bp    = (const float*)d_in[9];
  float* out = (float*)d_out;
  char* ws = (char*)d_ws;

  u16*   W0p  = (u16*)  (ws + OFF_W0P);
  u16*   W1p  = (u16*)  (ws + OFF_W1P);
  float* T0   = (float*)(ws + OFF_T0);
  float* b1   = (float*)(ws + OFF_B1);
  u8*    pidx = (u8*)   (ws + OFF_PIDX);
  u16*   h0   = (u16*)  (ws + OFF_H0);
  u16*   h1   = (u16*)  (ws + OFF_H1);
  int*   sync = (int*)  (ws + OFF_SYNC);

  k_prep<<<512, 256, 0, stream>>>(Wih, Whh, bih, bhh, W0p, W1p, b1, h0, sync);
  k_pidx<<<64, 256, 0, stream>>>(inp, pidx);
  k_table<<<128, 256, 0, stream>>>(embed, Wih, bih, bhh, T0);

  k_fast<<<dim3(NWGL), dim3(256), 0, stream>>>(W0p, W1p, T0, b1, pidx, h0, h1, sync);
  k_check<<<64, 256, 0, stream>>>(sync, (u64*)h0);
  k_safe<<<dim3(96), dim3(256), 0, stream>>>(W0p, W1p, T0, b1, pidx, h0, h1, sync);

  // h1[2047] lives in buffer (2047 % 4) == 3
  k_final<<<64, 256, 0, stream>>>(h1 + 3*HS, ln_g, ln_b, Wp, bp, out);
}

// Round 11
// 8321.195 us; speedup vs baseline: 2.1756x; 1.1983x over previous
//
#include <hip/hip_runtime.h>

typedef unsigned short u16;
typedef unsigned char u8;
typedef unsigned long long u64;
typedef __attribute__((ext_vector_type(8))) _Float16 half8;
typedef __attribute__((ext_vector_type(4))) float f32x4;
typedef __attribute__((ext_vector_type(4))) unsigned int u32x4;

#define MFMA16(a,b,c) __builtin_amdgcn_mfma_f32_16x16x32_f16((a),(b),(c),0,0,0)

#define S_LEN 2048
#define HS (64*512)    // u16 elements per h buffer [64][512]
#define NB0 4          // h0 ring buffers
#define NB1 4          // h1 ring buffers
#define NGRP 4         // independent batch groups (16 batch rows each)

// ---------- ws layout (bytes) ----------
#define OFF_W0P  0            // fp16 [8 wgi][4 wv][4 g][16 m][512 k]   2 MB
#define OFF_W1P  2097152      // fp16 [16 wgi][2 ch][2 kh][4 g][16][512] 4 MB
#define OFF_T0   6291456      // f32 [16 pair][4 gate][512 col]         128 KB
#define OFF_B1   6422528      // f32 [4 gate][512 col]                  8 KB
#define OFF_PIDX 6430720      // u8 [2048][64]                          128 KB
#define OFF_H0   6561792      // fp16 4 x [64][512] (row-swizzled)      256 KB
#define OFF_H1   6823936      // fp16 4 x [64][512] (row-swizzled)      256 KB
#define OFF_FLAG 7086080      // int [4 grp][64]: fA(L0 waves)[0..31], fB(L1 ch)[32..63]

__device__ __forceinline__ u16 f2h(float f) {
  _Float16 h = (_Float16)f;
  return __builtin_bit_cast(u16, h);
}
__device__ __forceinline__ float sigf(float x)   { return 1.f/(1.f + __expf(-x)); }
__device__ __forceinline__ float tanhf_(float x) { return 2.f/(1.f + __expf(-2.f*x)) - 1.f; }

// device-coherent 16B load (bypass L1/L2; served at coherence point)
__device__ __forceinline__ u32x4 gload16(const void* p) {
  u32x4 d;
  asm volatile("global_load_dwordx4 %0, %1, off sc0 sc1"
               : "=&v"(d) : "v"(p) : "memory");
  return d;
}
// 8B h store as return-less atomic swap: executes AT the coherence point and
// leaves the line resident there (vs sc0 sc1 write-through streaming to HBM).
__device__ __forceinline__ void store_h4(void* p, const float* hv) {
  union { u64 q; _Float16 h[4]; } u;
  u.h[0] = (_Float16)hv[0]; u.h[1] = (_Float16)hv[1];
  u.h[2] = (_Float16)hv[2]; u.h[3] = (_Float16)hv[3];
  asm volatile("global_atomic_swap_x2 %0, %1, off" :: "v"(p), "v"(u.q) : "memory");
}
__device__ __forceinline__ void store_flag(int* p, int v) {
  asm volatile("global_atomic_swap %0, %1, off" :: "v"(p), "v"(v) : "memory");
}
// 64-flag poll: lane i watches fgrp[i]; lanes 0..31 need >= nA, 32..63 need >= nB.
// Monotonic flags + always-resident producers => deadlock-free. sleep(1) backoff.
__device__ __forceinline__ void pollv(const int* fgrp, int lane, int nA, int nB) {
  const int* p = fgrp + lane;
  const int need = (lane < 32) ? nA : nB;
  for (;;) {
    int v;
    asm volatile("global_load_dword %0, %1, off sc0 sc1\ns_waitcnt vmcnt(0)"
                 : "=v"(v) : "v"(p) : "memory");
    if (__all(v >= need)) break;
    __builtin_amdgcn_s_sleep(1);
  }
}

// ---------- prep: weight permute+convert, bias sum, zero h, reset flags ----------
__global__ void k_prep(const float* __restrict__ Wih, const float* __restrict__ Whh,
                       const float* __restrict__ bih, const float* __restrict__ bhh,
                       u16* __restrict__ W0p, u16* __restrict__ W1p,
                       float* __restrict__ b1, u16* __restrict__ hz, int* __restrict__ flags)
{
  int i = blockIdx.x * blockDim.x + threadIdx.x;
  int st = gridDim.x * blockDim.x;
  // W0p[wgi][wv][g][m][k] <- Whh0[g*512 + (wgi*4+wv)*16 + m][k]
  for (int e = i; e < 8*4*4*16*512; e += st) {
    int k = e & 511, m = (e >> 9) & 15, g = (e >> 13) & 3, wv = (e >> 15) & 3, wgi = e >> 17;
    int row = g*512 + (wgi*4 + wv)*16 + m;
    W0p[e] = f2h(Whh[row*512 + k]);
  }
  // W1p[wgi][ch][kh][g][m][k] <- (kh?Whh1:Wih1)[g*512 + wgi*32 + ch*16 + m][k]
  for (int e = i; e < 16*2*2*4*16*512; e += st) {
    int k = e & 511, m = (e >> 9) & 15, g = (e >> 13) & 3, kh = (e >> 15) & 1,
        ch = (e >> 16) & 1, wgi = e >> 17;
    int row = g*512 + wgi*32 + ch*16 + m;
    const float* src = kh ? Whh : Wih;
    W1p[e] = f2h(src[2048*512 + row*512 + k]);
  }
  for (int e = i; e < 4*512; e += st) b1[e] = bih[2048 + e] + bhh[2048 + e];
  for (int e = i; e < (NB0 + NB1)*HS; e += st) hz[e] = 0;
  for (int e = i; e < NGRP*64; e += st) flags[e] = 0;
}

// ---------- pidx: pair index per (t,b), int32/int64 auto-detect ----------
__global__ void k_pidx(const int* __restrict__ inp32, u8* __restrict__ pidx)
{
  __shared__ int is64s;
  if (threadIdx.x == 0) {
    int z = 0;
    for (int t = 0; t < 64; ++t) z |= inp32[2*t + 1];
    is64s = (z == 0) ? 1 : 0;
  }
  __syncthreads();
  const int is64 = is64s;
  int i = blockIdx.x * blockDim.x + threadIdx.x;
  int st = gridDim.x * blockDim.x;
  for (int e = i; e < S_LEN*64; e += st) {
    int t = e >> 6, b = e & 63;
    int i0 = b * S_LEN + t;
    int i1 = 64 * S_LEN + b * S_LEN + t;
    int a = is64 ? inp32[2*i0] : inp32[i0];
    int c = is64 ? inp32[2*i1] : inp32[i1];
    pidx[e] = (u8)(a * 4 + c);
  }
}

// ---------- table: T0[p][g*512+j] = (embed[a]+embed[c]) . Wih0[g*512+j] + bias0 ----------
__global__ void k_table(const float* __restrict__ embed, const float* __restrict__ Wih,
                        const float* __restrict__ bih, const float* __restrict__ bhh,
                        float* __restrict__ T0)
{
  int idx = blockIdx.x * blockDim.x + threadIdx.x;
  if (idx >= 16*2048) return;
  int p = idx >> 11, gj = idx & 2047;
  const float* ea = embed + (p >> 2) * 512;
  const float* ec = embed + (p & 3) * 512;
  const float* w  = Wih + gj * 512;
  float acc = bih[gj] + bhh[gj];
  for (int k = 0; k < 512; ++k) acc += (ea[k] + ec[k]) * w[k];
  T0[p * 2048 + gj] = acc;
}

// ---------- persistent 2-layer LSTM: 4 batch groups, per-wave flags, atomic h ----------
__global__ __launch_bounds__(256, 1) void k_lstm(
    const u16* __restrict__ W0p, const u16* __restrict__ W1p,
    const float* __restrict__ T0, const float* __restrict__ b1,
    const u8* __restrict__ pidx,
    u16* __restrict__ h0b, u16* __restrict__ h1b, int* __restrict__ flags)
{
  __shared__ __align__(16) u8 smem[40960];   // 32KB staging + 8KB xbuf
  const int tid  = threadIdx.x;
  const int lane = tid & 63, wave = tid >> 6;
  const int wg   = blockIdx.x;
  const int mrow = lane & 15;
  const int m4   = (lane >> 4) * 4;
  const int q16  = (lane >> 4) * 16;
  const int swm  = (mrow & 7) << 4;

  if (wg < 32) {
    // ===== layer 0: wave owns 16 cols x 4 gates, K=512; per-wave flag =====
    const int grp = wg >> 3, wgi = wg & 7;
    int* fgrp = flags + grp*64;
    const int jc = (wgi*4 + wave) * 16;
    const u16* wbase = W0p + (wgi*4 + wave) * 32768;
    half8 wa[4][16];
#pragma unroll
    for (int g = 0; g < 4; ++g)
#pragma unroll
      for (int ks = 0; ks < 16; ++ks)
        wa[g][ks] = *(const half8*)(wbase + (g*16 + mrow)*512 + ks*32 + (lane >> 4)*8);
    const int bg = grp*16 + mrow;   // global batch row
    float cs[4] = {0.f, 0.f, 0.f, 0.f};
    int p = pidx[bg];
    f32x4 tg[4];
#pragma unroll
    for (int g = 0; g < 4; ++g) tg[g] = *(const f32x4*)(T0 + p*2048 + jc + m4 + g*512);
    for (int t = 0; t < S_LEN; ++t) {
      if (wave == 0) pollv(fgrp, lane, t, t - (NB0 - 1));
      __syncthreads();                 // flags ready + prev-step LDS reads done
      const u16* hr = h0b + ((t + NB0 - 1) % NB0) * HS;   // h0[t-1]
      u16*       hw = h0b + (t % NB0) * HS;               // h0[t]
      // ---- linear staged copy: 16KB group slice -> LDS ----
      {
        const char* gs = (const char*)hr + grp*16384;
        u32x4 d0 = gload16(gs + tid*16);
        u32x4 d1 = gload16(gs + tid*16 + 4096);
        u32x4 d2 = gload16(gs + tid*16 + 8192);
        u32x4 d3 = gload16(gs + tid*16 + 12288);
        asm volatile("s_waitcnt vmcnt(0)" ::: "memory");
        __builtin_amdgcn_sched_barrier(0);
        *(u32x4*)(smem + tid*16        ) = d0;
        *(u32x4*)(smem + tid*16 +  4096) = d1;
        *(u32x4*)(smem + tid*16 +  8192) = d2;
        *(u32x4*)(smem + tid*16 + 12288) = d3;
      }
      __syncthreads();
      half8 bf[16];
#pragma unroll
      for (int ks = 0; ks < 16; ++ks)
        bf[ks] = *(const half8*)(smem + mrow*1024 + ((ks*64 + q16) ^ swm));
      f32x4 acc[4] = {{0,0,0,0},{0,0,0,0},{0,0,0,0},{0,0,0,0}};
#pragma unroll
      for (int ks = 0; ks < 16; ++ks)
#pragma unroll
        for (int g = 0; g < 4; ++g)
          acc[g] = MFMA16(wa[g][ks], bf[ks], acc[g]);
      float hv[4];
#pragma unroll
      for (int r = 0; r < 4; ++r) {
        float gi = acc[0][r] + tg[0][r];
        float gf = acc[1][r] + tg[1][r];
        float gg = acc[2][r] + tg[2][r];
        float go = acc[3][r] + tg[3][r];
        float cc = sigf(gf)*cs[r] + sigf(gi)*tanhf_(gg);
        cs[r] = cc;
        hv[r] = sigf(go)*tanhf_(cc);
      }
      // swizzled atomic store, per-wave drain, per-wave flag (no barrier)
      store_h4((char*)hw + bg*1024 + (((jc + m4)*2) ^ ((bg & 7) << 4)), hv);
      asm volatile("s_waitcnt vmcnt(0)" ::: "memory");
      if (lane == 0) store_flag(fgrp + wgi*4 + wave, t + 1);
      // T0 prefetch AFTER the flag (off critical path)
      if (t + 1 < S_LEN) {
        int pn = pidx[(t+1)*64 + bg];
#pragma unroll
        for (int g = 0; g < 4; ++g)
          tg[g] = *(const f32x4*)(T0 + pn*2048 + jc + m4 + g*512);
      }
#pragma unroll
      for (int g = 0; g < 4; ++g)
#pragma unroll
        for (int ks = 0; ks < 16; ++ks)
          asm volatile("" : "+v"(wa[g][ks]));   // keep weights VGPR-resident
    }
  } else {
    // ===== layer 1: wave = (ch, kh); kh0 waves finish + publish per-ch flag =====
    const int w1 = wg - 32;
    const int grp = w1 >> 4, wgi = w1 & 15;
    int* fgrp = flags + grp*64;
    const int kh = wave & 1, ch = wave >> 1;
    const int jc = wgi*32 + ch*16;
    const u16* wbase = W1p + ((wgi*2 + ch)*2 + kh) * 32768;
    half8 wa[4][16];
#pragma unroll
    for (int g = 0; g < 4; ++g)
#pragma unroll
      for (int ks = 0; ks < 16; ++ks)
        wa[g][ks] = *(const half8*)(wbase + (g*16 + mrow)*512 + ks*32 + (lane >> 4)*8);
    const int bg = grp*16 + mrow;
    f32x4* xbuf = (f32x4*)(smem + 32768);
    f32x4 big[4];
#pragma unroll
    for (int g = 0; g < 4; ++g) big[g] = *(const f32x4*)(b1 + g*512 + jc + m4);
    const int shalf = tid >> 7;          // 0: stage h0 slice, 1: stage h1 slice
    const int sidx  = tid & 127;
    float cs[4] = {0.f, 0.f, 0.f, 0.f};
    for (int w = 1; w <= S_LEN; ++w) {
      const int u = w - 1;               // computing h1[u]
      if (wave == 0) pollv(fgrp, lane, w, w - 1);
      __syncthreads();
      const u16* h0s = h0b + (u % NB0) * HS;               // h0[u]
      const u16* h1s = h1b + ((u + NB1 - 1) % NB1) * HS;   // h1[u-1]
      u16* hw = h1b + (u % NB1) * HS;                      // h1[u]
      {
        const char* gs = (const char*)(shalf ? h1s : h0s) + grp*16384;
        char* ls = (char*)smem + shalf*16384;
        u32x4 d[8];
#pragma unroll
        for (int j = 0; j < 8; ++j) d[j] = gload16(gs + sidx*16 + j*2048);
        asm volatile("s_waitcnt vmcnt(0)" ::: "memory");
        __builtin_amdgcn_sched_barrier(0);
#pragma unroll
        for (int j = 0; j < 8; ++j) *(u32x4*)(ls + sidx*16 + j*2048) = d[j];
      }
      __syncthreads();
      const char* lsrc = (const char*)smem + kh*16384;
      half8 bf[16];
#pragma unroll
      for (int ks = 0; ks < 16; ++ks)
        bf[ks] = *(const half8*)(lsrc + mrow*1024 + ((ks*64 + q16) ^ swm));
      f32x4 acc[4] = {{0,0,0,0},{0,0,0,0},{0,0,0,0},{0,0,0,0}};
#pragma unroll
      for (int ks = 0; ks < 16; ++ks)
#pragma unroll
        for (int g = 0; g < 4; ++g)
          acc[g] = MFMA16(wa[g][ks], bf[ks], acc[g]);
      if (kh == 1) {
#pragma unroll
        for (int g = 0; g < 4; ++g)
          xbuf[(ch*4 + g)*64 + lane] = acc[g];
      }
      __syncthreads();
      if (kh == 0) {
#pragma unroll
        for (int g = 0; g < 4; ++g)
          acc[g] += xbuf[(ch*4 + g)*64 + lane];
        float hv[4];
#pragma unroll
        for (int r = 0; r < 4; ++r) {
          float gi = acc[0][r] + big[0][r];
          float gf = acc[1][r] + big[1][r];
          float gg = acc[2][r] + big[2][r];
          float go = acc[3][r] + big[3][r];
          float cc = sigf(gf)*cs[r] + sigf(gi)*tanhf_(gg);
          cs[r] = cc;
          hv[r] = sigf(go)*tanhf_(cc);
        }
        store_h4((char*)hw + bg*1024 + (((jc + m4)*2) ^ ((bg & 7) << 4)), hv);
        asm volatile("s_waitcnt vmcnt(0)" ::: "memory");
        if (lane == 0) store_flag(fgrp + 32 + wgi*2 + ch, w);
      }
#pragma unroll
      for (int g = 0; g < 4; ++g)
#pragma unroll
        for (int ks = 0; ks < 16; ++ks)
          asm volatile("" : "+v"(wa[g][ks]));
    }
  }
}

// ---------- finalize: LayerNorm + projection from h1[2047] (fp16, swizzled rows) ----------
__global__ __launch_bounds__(256) void k_final(
    const u16* __restrict__ h1last, const float* __restrict__ ln_g,
    const float* __restrict__ ln_b, const float* __restrict__ Wp,
    const float* __restrict__ bp, float* __restrict__ out)
{
  __shared__ float sb[8];
  __shared__ float sred[4];
  const int b = blockIdx.x, tid = threadIdx.x;
  const char* hrow = (const char*)h1last + b * 1024;
  const int sw = (b & 7) << 4;
  float v1 = (float)*(const _Float16*)(hrow + ((tid*2) ^ sw));
  float v2 = (float)*(const _Float16*)(hrow + (((tid + 256)*2) ^ sw));
  float s1 = v1 + v2, s2 = v1*v1 + v2*v2;
#pragma unroll
  for (int o = 32; o; o >>= 1) { s1 += __shfl_down(s1, o); s2 += __shfl_down(s2, o); }
  if ((tid & 63) == 0) { sb[tid >> 6] = s1; sb[4 + (tid >> 6)] = s2; }
  __syncthreads();
  float S1 = sb[0] + sb[1] + sb[2] + sb[3];
  float S2 = sb[4] + sb[5] + sb[6] + sb[7];
  float mu = S1 * (1.f/512.f);
  float var = S2 * (1.f/512.f) - mu*mu;
  float inv = rsqrtf(var + 1e-5f);
  float acc = ((v1 - mu)*inv*ln_g[tid]       + ln_b[tid])       * Wp[tid]
            + ((v2 - mu)*inv*ln_g[tid + 256] + ln_b[tid + 256]) * Wp[tid + 256];
#pragma unroll
  for (int o = 32; o; o >>= 1) acc += __shfl_down(acc, o);
  if ((tid & 63) == 0) sred[tid >> 6] = acc;
  __syncthreads();
  if (tid == 0) out[b] = sred[0] + sred[1] + sred[2] + sred[3] + bp[0];
}

extern "C" void kernel_launch(void* const* d_in, const int* in_sizes, int n_in,
                              void* d_out, int out_size, void* d_ws, size_t ws_size,
                              hipStream_t stream) {
  (void)in_sizes; (void)n_in; (void)out_size; (void)ws_size;
  const int*   inp   = (const int*)d_in[0];
  const float* embed = (const float*)d_in[1];
  const float* Wih   = (const float*)d_in[2];
  const float* Whh   = (const float*)d_in[3];
  const float* bih   = (const float*)d_in[4];
  const float* bhh   = (const float*)d_in[5];
  const float* ln_g  = (const float*)d_in[6];
  const float* ln_b  = (const float*)d_in[7];
  const float* Wp    = (const float*)d_in[8];
  const float* bp    = (const float*)d_in[9];
  float* out = (float*)d_out;
  char* ws = (char*)d_ws;

  u16*   W0p  = (u16*)  (ws + OFF_W0P);
  u16*   W1p  = (u16*)  (ws + OFF_W1P);
  float* T0   = (float*)(ws + OFF_T0);
  float* b1   = (float*)(ws + OFF_B1);
  u8*    pidx = (u8*)   (ws + OFF_PIDX);
  u16*   h0   = (u16*)  (ws + OFF_H0);
  u16*   h1   = (u16*)  (ws + OFF_H1);
  int*   flags= (int*)  (ws + OFF_FLAG);

  k_prep<<<512, 256, 0, stream>>>(Wih, Whh, bih, bhh, W0p, W1p, b1, h0, flags);
  k_pidx<<<64, 256, 0, stream>>>(inp, pidx);
  k_table<<<128, 256, 0, stream>>>(embed, Wih, bih, bhh, T0);

  k_lstm<<<dim3(96), dim3(256), 0, stream>>>(W0p, W1p, T0, b1, pidx, h0, h1, flags);

  // h1[2047] lives in buffer (2047 % 4) == 3
  k_final<<<64, 256, 0, stream>>>(h1 + 3*HS, ln_g, ln_b, Wp, bp, out);
}